// Round 25
// baseline (310.940 us; speedup 1.0000x reference)
//
#include <hip/hip_runtime.h>

typedef unsigned char  u8;
typedef unsigned short u16;
typedef unsigned int   u32;
typedef __attribute__((ext_vector_type(4))) float f32x4;
typedef __attribute__((ext_vector_type(8))) __bf16 bf16x8;
typedef __attribute__((ext_vector_type(4))) u32  u32x4;
typedef __attribute__((ext_vector_type(2))) u32  u32x2;

__device__ __forceinline__ float bf2f(u16 h){ u32 u = ((u32)h)<<16; return __builtin_bit_cast(float, u); }
__device__ __forceinline__ u16  f2bf(float f){
  u32 u = __builtin_bit_cast(u32, f);
  u32 r = u + 0x7FFFu + ((u>>16)&1u);
  return (u16)(r>>16);
}

typedef const __attribute__((address_space(1))) u32 gas_u32;
typedef __attribute__((address_space(3))) u32 las_u32;
__device__ __forceinline__ void gll16(const void* g, void* l){
  __builtin_amdgcn_global_load_lds((gas_u32*)g, (las_u32*)l, 16, 0, 0);
}

__device__ __forceinline__ f32x4 mfma16(bf16x8 a, bf16x8 b, f32x4 c){
  return __builtin_amdgcn_mfma_f32_16x16x32_bf16(a, b, c, 0, 0, 0);
}

__device__ __forceinline__ bf16x8 ldsr8(const u16* p){
  u32x4 v = *(const u32x4*)p;
  return __builtin_bit_cast(bf16x8, v);
}

// XCD co-locate remap (A-panel-shared GEMMs: same-m blocks on one XCD)
__device__ __forceinline__ void xcd_remap(int &m_idx, int &n_idx){
  const int Mt = gridDim.x;
  const int fid = blockIdx.x + Mt*blockIdx.y;
  const int xcd = fid & 7, k = fid >> 3;
  const int mpx = Mt >> 3;
  m_idx = xcd*mpx + (k % mpx);
  n_idx = k / mpx;
}

// ------- prologue A: batch cvt + weight cvt + conv1 weight repack -------
__global__ __launch_bounds__(256)
void prep_big(const float* __restrict__ batch,
              const float* __restrict__ wq, const float* __restrict__ wk,
              const float* __restrict__ wv, const float* __restrict__ wo,
              const float* __restrict__ w2, const float* __restrict__ w1,
              u16* __restrict__ batchc, u16* __restrict__ wqc, u16* __restrict__ w1r)
{
  const int bid = blockIdx.x, tid = threadIdx.x;
  if (bid < 4096){
    const int i = bid*1024 + tid*4;
    f32x4 v = *(const f32x4*)&batch[i];
    u32x2 o;
    o[0] = (u32)f2bf(v[0]) | ((u32)f2bf(v[1])<<16);
    o[1] = (u32)f2bf(v[2]) | ((u32)f2bf(v[3])<<16);
    *(u32x2*)&batchc[i] = o;
  } else if (bid < 4608){
    const int i = (bid-4096)*1024 + tid*4;
    const float* s; int off;
    if      (i < 65536)  { s = wq; off = i; }
    else if (i < 131072) { s = wk; off = i - 65536; }
    else if (i < 196608) { s = wv; off = i - 131072; }
    else if (i < 262144) { s = wo; off = i - 196608; }
    else                 { s = w2; off = i - 262144; }
    f32x4 v = *(const f32x4*)&s[off];
    u32x2 o;
    o[0] = (u32)f2bf(v[0]) | ((u32)f2bf(v[1])<<16);
    o[1] = (u32)f2bf(v[2]) | ((u32)f2bf(v[3])<<16);
    *(u32x2*)&wqc[i] = o;
  } else {
    const int idx = (bid-4608)*256 + tid;
    const int c = idx / 2304;
    const int t = idx - c*2304;
    const int i = t / 9;
    const int kk = t - i*9;
    w1r[c*2304 + kk*256 + i] = f2bf(w1[idx]);
  }
}

// ------- prologue B: params + mask canon + lengths -------
__global__ __launch_bounds__(256)
void prep_small(const float* p0,const float* p1,const float* p2,const float* p3,
                const float* p4,const float* p5,const float* p6,const float* p7,
                const float* p8,const float* p9,
                u16* __restrict__ params, const void* __restrict__ mraw,
                u16* __restrict__ cmask, u32* __restrict__ lengths)
{
  const int bid = blockIdx.x, tid = threadIdx.x;
  if (bid == 0){
    const float* ps[10] = {p0,p1,p2,p3,p4,p5,p6,p7,p8,p9};
    const int  off[10] = {0,256,512,768,1024,1280,1536,1792,2048,3072};
    const int  len[10] = {256,256,256,256,256,256,256,256,1024,256};
    for (int a=0;a<10;++a)
      for (int i=tid;i<len[a];i+=256)
        params[off[a]+i] = f2bf(ps[a][i]);
  } else {
    const u8*  pb8  = (const u8*)mraw;
    const u16* pb16 = (const u16*)mraw;
    const u32* pb32 = (const u32*)mraw;
    __shared__ int bad8, bad16, nz8, nz16;
    __shared__ int slen[8];
    if (tid==0){ bad8=0; bad16=0; nz8=0; nz16=0; }
    if (tid<8) slen[tid] = 2048;
    __syncthreads();
    for (int i=tid;i<16384;i+=256){
      u8 v = pb8[i]; int row = i & 2047;
      if (v>1) atomicOr(&bad8,1);
      if (v){ atomicOr(&nz8,1); if (row<1024) atomicOr(&bad8,1); }
      if (row>0 && pb8[i-1]==1 && v==0) atomicOr(&bad8,1);
    }
    for (int i=tid;i<8192;i+=256){
      u16 v = pb16[i]; int row = i & 2047;
      if (!(v==0 || v==0x3F80)) atomicOr(&bad16,1);
      if (v){ atomicOr(&nz16,1); if (row<1024) atomicOr(&bad16,1); }
      if (row>0 && pb16[i-1]==0x3F80 && v==0) atomicOr(&bad16,1);
    }
    __syncthreads();
    const int mode = (!bad8 && nz8) ? 1 : ((!bad16 && nz16) ? 2 : 0);
    for (int i=tid;i<16384;i+=256){
      u16 m;
      if (mode==1)      m = pb8[i]  ? 1 : 0;
      else if (mode==2) m = pb16[i] ? 1 : 0;
      else              m = pb32[i] ? 1 : 0;
      cmask[i] = m;
      if (m) atomicMin(&slen[i>>11], i&2047);
    }
    __syncthreads();
    if (tid<8) lengths[tid] = (u32)slen[tid];
  }
}

// ------- zero the 4-row halos of seq1p [8][2056][256] (after VT is dead) -------
__global__ __launch_bounds__(256)
void zero_halo(u16* __restrict__ seq1p)
{
  const int idx = blockIdx.x*256 + threadIdx.x;   // 16384
  const int b = idx>>11, t = idx&2047;
  const int r = t>>8, c = t&255;
  const int row = (r<4) ? r : (2052 + r - 4);
  seq1p[((size_t)b*2056 + row)*256 + c] = 0;
}

// ------- fused QKV GEMM -------
__global__ __launch_bounds__(256)
void gemm_qkv(const u16* __restrict__ A, const u16* __restrict__ W,
              const u16* __restrict__ bias, u16* __restrict__ qbase,
              const u16* __restrict__ cmask)
{
  __shared__ __align__(16) u16 aL[2][4096];
  __shared__ __align__(16) u16 bL[2][4096];
  const int tid = threadIdx.x, lane = tid&63, w = tid>>6;
  const int wm = w>>1, wn = w&1, lr = lane&15, lg = lane>>4;
  int mi, ni; xcd_remap(mi, ni);
  const int m0 = mi*128, n0 = ni*128;
  if (cmask[m0] != 0) return;

  f32x4 acc[4][4];
#pragma unroll
  for (int i=0;i<4;++i)
#pragma unroll
    for (int j=0;j<4;++j) acc[i][j] = f32x4{0.f,0.f,0.f,0.f};

  auto stage = [&](int buf, int kk){
#pragma unroll
    for (int i=0;i<2;++i){
      const int chunk = w*2+i;
      const int boff  = chunk*1024 + lane*16;
      const int r = boff>>6;
      const int cb = (boff&63) ^ (((r>>1)&3)<<4);
      const int c = cb>>1;
      gll16(&A[(size_t)(m0+r)*256 + kk*32 + c], &aL[buf][chunk*512]);
      gll16(&W[(size_t)(n0+r)*256 + kk*32 + c], &bL[buf][chunk*512]);
    }
  };

  stage(0,0);
  __syncthreads();
  for (int kk=0; kk<8; ++kk){
    if (kk+1<8) stage((kk+1)&1, kk+1);
    const u16* ab = aL[kk&1];
    const u16* bb = bL[kk&1];
    bf16x8 af[4], bv[4];
#pragma unroll
    for (int m=0;m<4;++m){
      const int ra = wm*64+m*16+lr;
      af[m] = ldsr8(&ab[(ra*64 + ((lg*16) ^ (((ra>>1)&3)<<4)))>>1]);
    }
#pragma unroll
    for (int n=0;n<4;++n){
      const int rb = wn*64+n*16+lr;
      bv[n] = ldsr8(&bb[(rb*64 + ((lg*16) ^ (((rb>>1)&3)<<4)))>>1]);
    }
#pragma unroll
    for (int m=0;m<4;++m)
#pragma unroll
      for (int n=0;n<4;++n)
        acc[m][n] = mfma16(af[m], bv[n], acc[m][n]);
    __syncthreads();
  }
#pragma unroll
  for (int m=0;m<4;++m)
#pragma unroll
    for (int n=0;n<4;++n)
#pragma unroll
      for (int r=0;r<4;++r){
        const int row = m0 + wm*64 + m*16 + lg*4 + r;
        const int col = n0 + wn*64 + n*16 + lr;
        const int which = col>>8, ch = col&255;
        float v = acc[m][n][r] + bf2f(bias[col]);
        qbase[(size_t)which*4194304 + (size_t)row*256 + ch] = f2bf(v);
      }
}

// ------- conv1: 128x128 tile, 4 waves, 3-buffer lead-2 pipeline, raw barriers + counted vmcnt -------
__global__ __launch_bounds__(256, 4)
void conv1_gemm(const u16* __restrict__ Ap, const u16* __restrict__ W1r,
                const u16* __restrict__ b1, u16* __restrict__ Hout,
                const u16* __restrict__ cmask)
{
  __shared__ __align__(16) u16 aL[3][4096];
  __shared__ __align__(16) u16 bL[3][4096];
  const int tid = threadIdx.x, lane = tid&63, w = tid>>6;
  const int wm = w>>1, wn = w&1, lr = lane&15, lg = lane>>4;
  int mi, ni; xcd_remap(mi, ni);
  const int m0 = mi*128, n0 = ni*128;
  if (cmask[m0] != 0) return;
  const int b = m0>>11, s0 = m0&2047;
  const size_t abase = ((size_t)b*2056 + s0)*256;

  f32x4 acc[4][4];
#pragma unroll
  for (int i=0;i<4;++i)
#pragma unroll
    for (int j=0;j<4;++j) acc[i][j] = f32x4{0.f,0.f,0.f,0.f};

  // 4 gll16 per thread per stage
  auto stage = [&](int buf, int kk){
    const int tap = kk>>3, ch0 = (kk&7)*32;
#pragma unroll
    for (int i=0;i<2;++i){
      const int chunk = w*2+i;
      const int boff  = chunk*1024 + lane*16;
      const int r = boff>>6;
      const int cb = (boff&63) ^ (((r>>1)&3)<<4);
      const int c = cb>>1;
      gll16(&Ap[abase + (size_t)(tap + r)*256 + ch0 + c], &aL[buf][chunk*512]);
      gll16(&W1r[(size_t)(n0+r)*2304 + kk*32 + c], &bL[buf][chunk*512]);
    }
  };

  // prologue: prefetch steps 0 and 1
  stage(0, 0);
  stage(1, 1);

  for (int kk=0; kk<72; ++kk){
    // barrier: all waves finished computing kk-1 -> safe to overwrite buf[(kk+2)%3]
    asm volatile("" ::: "memory");
    __builtin_amdgcn_s_barrier();
    asm volatile("" ::: "memory");
    if (kk+2 < 72){
      stage((kk+2)%3, kk+2);
      // drain everything except the 4 loads just issued (step kk+2);
      // step kk was drained at iter kk-1, step kk+1 is ~1 iteration old (cheap)
      asm volatile("s_waitcnt vmcnt(4)" ::: "memory");
    } else {
      asm volatile("s_waitcnt vmcnt(0)" ::: "memory");
    }
    const u16* ab = aL[kk%3];
    const u16* bb = bL[kk%3];
    bf16x8 af[4], bv[4];
#pragma unroll
    for (int m=0;m<4;++m){
      const int ra = wm*64+m*16+lr;
      af[m] = ldsr8(&ab[(ra*64 + ((lg*16) ^ (((ra>>1)&3)<<4)))>>1]);
    }
#pragma unroll
    for (int n=0;n<4;++n){
      const int rb = wn*64+n*16+lr;
      bv[n] = ldsr8(&bb[(rb*64 + ((lg*16) ^ (((rb>>1)&3)<<4)))>>1]);
    }
    __builtin_amdgcn_s_setprio(1);
#pragma unroll
    for (int m=0;m<4;++m)
#pragma unroll
      for (int n=0;n<4;++n)
        acc[m][n] = mfma16(af[m], bv[n], acc[m][n]);
    __builtin_amdgcn_s_setprio(0);
  }
#pragma unroll
  for (int m=0;m<4;++m)
#pragma unroll
    for (int n=0;n<4;++n)
#pragma unroll
      for (int r=0;r<4;++r){
        const int row = m0 + wm*64 + m*16 + lg*4 + r;
        const int col = n0 + wn*64 + n*16 + lr;
        float v = acc[m][n][r] + bf2f(b1[col]);
        v = v>0.f ? v : 0.f;
        Hout[(size_t)row*1024 + col] = f2bf(v);
      }
}

// ------- fused outproj + residual(batchc) + LayerNorm1 + mask -> seq1p (padded bf16) -------
__global__ __launch_bounds__(512)
void outproj_ln(const u16* __restrict__ Ctx, const u16* __restrict__ woc,
                const u16* __restrict__ bo, const u16* __restrict__ batchc,
                const u16* __restrict__ g1, const u16* __restrict__ be1,
                const u16* __restrict__ cmask, u16* __restrict__ seq1p)
{
  __shared__ __align__(16) u16 aL[2][2048];
  __shared__ __align__(16) u16 bL[2][8192];
  __shared__ float red[2][32][4][2];
  const int tid = threadIdx.x, lane = tid&63, w = tid>>6;
  const int wm = w>>2, wn = w&3, lr = lane&15, lg = lane>>4;
  int mi, ni; xcd_remap(mi, ni); (void)ni;
  const int m0 = mi*64;
  if (cmask[m0] != 0){
    for (int i=tid;i<64*128;i+=512){
      const int rr = i>>7, cc = (i&127)*2;
      const int row = m0 + rr;
      const size_t prow = (size_t)row + (row>>11)*8 + 4;
      *(u32*)&seq1p[prow*256 + cc] = 0u;
    }
    return;
  }

  f32x4 acc[2][4];
#pragma unroll
  for (int i=0;i<2;++i)
#pragma unroll
    for (int j=0;j<4;++j) acc[i][j] = f32x4{0.f,0.f,0.f,0.f};

  auto stage = [&](int buf, int kk){
    if (w < 4){
      const int boff = w*1024 + lane*16;
      const int r = boff>>6;
      const int cb = (boff&63) ^ (((r>>1)&3)<<4);
      gll16(&Ctx[(size_t)(m0+r)*256 + kk*32 + (cb>>1)], &aL[buf][w*512]);
    }
#pragma unroll
    for (int i=0;i<2;++i){
      const int chunk = w*2+i;
      const int boff = chunk*1024 + lane*16;
      const int r = boff>>6;
      const int cb = (boff&63) ^ (((r>>1)&3)<<4);
      gll16(&woc[(size_t)r*256 + kk*32 + (cb>>1)], &bL[buf][chunk*512]);
    }
  };

  stage(0,0);
  __syncthreads();
  for (int kk=0; kk<8; ++kk){
    if (kk+1<8) stage((kk+1)&1, kk+1);
    const u16* ab = aL[kk&1];
    const u16* bb = bL[kk&1];
    bf16x8 af[2], bv[4];
#pragma unroll
    for (int m=0;m<2;++m){
      const int ra = wm*32+m*16+lr;
      af[m] = ldsr8(&ab[(ra*64 + ((lg*16) ^ (((ra>>1)&3)<<4)))>>1]);
    }
#pragma unroll
    for (int n=0;n<4;++n){
      const int rb = wn*64+n*16+lr;
      bv[n] = ldsr8(&bb[(rb*64 + ((lg*16) ^ (((rb>>1)&3)<<4)))>>1]);
    }
#pragma unroll
    for (int m=0;m<2;++m)
#pragma unroll
      for (int n=0;n<4;++n)
        acc[m][n] = mfma16(af[m], bv[n], acc[m][n]);
    __syncthreads();
  }
#pragma unroll
  for (int m=0;m<2;++m)
#pragma unroll
    for (int r=0;r<4;++r){
      float s = 0.f, qq = 0.f;
#pragma unroll
      for (int n=0;n<4;++n){
        const int col = wn*64 + n*16 + lr;
        const int row = m0 + wm*32 + m*16 + lg*4 + r;
        float val = acc[m][n][r] + bf2f(bo[col]) + bf2f(batchc[(size_t)row*256 + col]);
        acc[m][n][r] = val;
        s += val; qq += val*val;
      }
#pragma unroll
      for (int x=1;x<16;x<<=1){ s += __shfl_xor(s, x); qq += __shfl_xor(qq, x); }
      if (lr == 0){
        const int lrow = m*16 + lg*4 + r;
        red[wm][lrow][wn][0] = s;
        red[wm][lrow][wn][1] = qq;
      }
    }
  __syncthreads();
#pragma unroll
  for (int m=0;m<2;++m)
#pragma unroll
    for (int r=0;r<4;++r){
      const int lrow = m*16 + lg*4 + r;
      const float S = red[wm][lrow][0][0]+red[wm][lrow][1][0]+red[wm][lrow][2][0]+red[wm][lrow][3][0];
      const float Q = red[wm][lrow][0][1]+red[wm][lrow][1][1]+red[wm][lrow][2][1]+red[wm][lrow][3][1];
      const float mu = S*(1.f/256.f);
      const float rs = rsqrtf(Q*(1.f/256.f) - mu*mu + 1e-5f);
      const int row = m0 + wm*32 + lrow;
      const int msk = cmask[row];
      const size_t prow = (size_t)row + (row>>11)*8 + 4;
#pragma unroll
      for (int n=0;n<4;++n){
        const int col = wn*64 + n*16 + lr;
        float y = (acc[m][n][r]-mu)*rs*bf2f(g1[col]) + bf2f(be1[col]);
        seq1p[prow*256 + col] = msk ? (u16)0 : f2bf(y);
      }
    }
}

// ------- fused conv2 + residual + LayerNorm2 + mask (f32 out) -------
__global__ __launch_bounds__(512)
void conv2_ln(const u16* __restrict__ Hh, const u16* __restrict__ w2c,
              const u16* __restrict__ b2, const u16* __restrict__ seq1p,
              const u16* __restrict__ g2, const u16* __restrict__ be2,
              const u16* __restrict__ cmask, float* __restrict__ out)
{
  __shared__ __align__(16) u16 aL[2][2048];
  __shared__ __align__(16) u16 bL[2][8192];
  __shared__ float red[2][32][4][2];
  const int tid = threadIdx.x, lane = tid&63, w = tid>>6;
  const int wm = w>>2, wn = w&3, lr = lane&15, lg = lane>>4;
  int mi, ni; xcd_remap(mi, ni); (void)ni;
  const int m0 = mi*64;
  if (cmask[m0] != 0) return;

  f32x4 acc[2][4];
#pragma unroll
  for (int i=0;i<2;++i)
#pragma unroll
    for (int j=0;j<4;++j) acc[i][j] = f32x4{0.f,0.f,0.f,0.f};

  auto stage = [&](int buf, int kk){
    if (w < 4){
      const int boff = w*1024 + lane*16;
      const int r = boff>>6;
      const int cb = (boff&63) ^ (((r>>1)&3)<<4);
      gll16(&Hh[(size_t)(m0+r)*1024 + kk*32 + (cb>>1)], &aL[buf][w*512]);
    }
#pragma unroll
    for (int i=0;i<2;++i){
      const int chunk = w*2+i;
      const int boff = chunk*1024 + lane*16;
      const int r = boff>>6;
      const int cb = (boff&63) ^ (((r>>1)&3)<<4);
      gll16(&w2c[(size_t)r*1024 + kk*32 + (cb>>1)], &bL[buf][chunk*512]);
    }
  };

  stage(0,0);
  __syncthreads();
  for (int kk=0; kk<32; ++kk){
    if (kk+1<32) stage((kk+1)&1, kk+1);
    const u16* ab = aL[kk&1];
    const u16* bb = bL[kk&1];
    bf16x8 af[2], bv[4];
#pragma unroll
    for (int m=0;m<2;++m){
      const int ra = wm*32+m*16+lr;
      af[m] = ldsr8(&ab[(ra*64 + ((lg*16) ^ (((ra>>1)&3)<<4)))>>1]);
    }
#pragma unroll
    for (int n=0;n<4;++n){
      const int rb = wn*64+n*16+lr;
      bv[n] = ldsr8(&bb[(rb*64 + ((lg*16) ^ (((rb>>1)&3)<<4)))>>1]);
    }
#pragma unroll
    for (int m=0;m<2;++m)
#pragma unroll
      for (int n=0;n<4;++n)
        acc[m][n] = mfma16(af[m], bv[n], acc[m][n]);
    __syncthreads();
  }
#pragma unroll
  for (int m=0;m<2;++m)
#pragma unroll
    for (int r=0;r<4;++r){
      float s = 0.f, qq = 0.f;
#pragma unroll
      for (int n=0;n<4;++n){
        const int col = wn*64 + n*16 + lr;
        const int row = m0 + wm*32 + m*16 + lg*4 + r;
        const size_t ri = ((size_t)row + (row>>11)*8 + 4)*256 + col;
        float val = acc[m][n][r] + bf2f(b2[col]) + bf2f(seq1p[ri]);
        acc[m][n][r] = val;
        s += val; qq += val*val;
      }
#pragma unroll
      for (int x=1;x<16;x<<=1){ s += __shfl_xor(s, x); qq += __shfl_xor(qq, x); }
      if (lr == 0){
        const int lrow = m*16 + lg*4 + r;
        red[wm][lrow][wn][0] = s;
        red[wm][lrow][wn][1] = qq;
      }
    }
  __syncthreads();
#pragma unroll
  for (int m=0;m<2;++m)
#pragma unroll
    for (int r=0;r<4;++r){
      const int lrow = m*16 + lg*4 + r;
      const float S = red[wm][lrow][0][0]+red[wm][lrow][1][0]+red[wm][lrow][2][0]+red[wm][lrow][3][0];
      const float Q = red[wm][lrow][0][1]+red[wm][lrow][1][1]+red[wm][lrow][2][1]+red[wm][lrow][3][1];
      const float mu = S*(1.f/256.f);
      const float rs = rsqrtf(Q*(1.f/256.f) - mu*mu + 1e-5f);
      const int row = m0 + wm*32 + lrow;
      const int msk = cmask[row];
#pragma unroll
      for (int n=0;n<4;++n){
        const int col = wn*64 + n*16 + lr;
        float y = (acc[m][n][r]-mu)*rs*bf2f(g2[col]) + bf2f(be2[col]);
        out[(size_t)row*256 + col] = msk ? 0.f : y;
      }
    }
}

// ------- V [16384][256] -> VT [b][h][128][2048] -------
__global__ __launch_bounds__(256)
void vtrans(const u16* __restrict__ V, u16* __restrict__ VT)
{
  __shared__ u16 t[64][72];
  const int tid = threadIdx.x;
  const int s0 = blockIdx.x*64;
  const int d0 = blockIdx.y*64;
#pragma unroll
  for (int i=0;i<2;++i){
    const int chunk = tid + i*256;
    const int sr = chunk>>3, c8 = (chunk&7)*8;
    u32x4 raw = *(const u32x4*)&V[(size_t)(s0+sr)*256 + d0 + c8];
#pragma unroll
    for (int j=0;j<4;++j){
      t[sr][c8+2*j]   = (u16)(raw[j]&0xffffu);
      t[sr][c8+2*j+1] = (u16)(raw[j]>>16);
    }
  }
  __syncthreads();
  const int b = s0>>11;
#pragma unroll
  for (int i=0;i<2;++i){
    const int chunk = tid + i*256;
    const int dr = chunk>>3, s8 = (chunk&7)*8;
    const int dg = d0 + dr;
    const int hh = dg>>7, dh = dg&127;
    u32x4 o;
#pragma unroll
    for (int j=0;j<4;++j)
      o[j] = (u32)t[s8+2*j][dr] | ((u32)t[s8+2*j+1][dr]<<16);
    *(u32x4*)&VT[((size_t)((b*2+hh)*128 + dh))*2048 + (s0&2047) + s8] = o;
  }
}

// ------- flash attention: q-tile 128, 8 waves, KVBLK=64, dbuf gll16, 1 barrier/tile -------
__global__ __launch_bounds__(512)
void attn_fwd(const u16* __restrict__ Q, const u16* __restrict__ Kb,
              const u16* __restrict__ VT, const u32* __restrict__ lengths,
              u16* __restrict__ ctx)
{
  __shared__ __align__(16) u16 kls[2][64*128];
  __shared__ __align__(16) u16 vtls[2][128*64];
  __shared__ __align__(16) u16 pls[8][16*64];
  const int tid = threadIdx.x, lane = tid&63, w = tid>>6;
  const int fid = blockIdx.x;
  const int pair = fid & 15;
  const int qt = fid >> 4;
  const int b  = pair >> 1;
  const int hh = pair & 1;
  const int q0 = qt*128;
  const int L  = (int)lengths[b];
  if (q0 >= L) return;
  const int nkt = (L + 63) >> 6;
  const int lr = lane&15, lg = lane>>4;
  u16* pw = pls[w];

  bf16x8 qf[4];
#pragma unroll
  for (int d=0;d<4;++d)
    qf[d] = *(const bf16x8*)&Q[((size_t)(b*2048+q0+w*16+lr))*256 + hh*128 + d*32 + lg*8];

  f32x4 oacc[8];
  float mrun[4], lrun[4];
#pragma unroll
  for (int n=0;n<8;++n) oacc[n] = f32x4{0.f,0.f,0.f,0.f};
#pragma unroll
  for (int r=0;r<4;++r){ mrun[r] = -1e30f; lrun[r] = 0.f; }

  const size_t kbase = (size_t)(b*2048)*256 + hh*128;
  const size_t vbase = (size_t)((b*2+hh)*128)*2048;

  auto stage = [&](int buf, int kt){
    const int kv0 = kt*64;
#pragma unroll
    for (int i=0;i<2;++i){
      const int chunk = w*2+i;
      const int boff = chunk*1024 + lane*16;
      const int r = boff>>8;
      const int cb = (boff&255) ^ ((r&7)<<4);
      gll16(&Kb[kbase + (size_t)(kv0+r)*256 + (cb>>1)], &kls[buf][chunk*512]);
    }
#pragma unroll
    for (int i=0;i<2;++i){
      const int chunk = w*2+i;
      const int boff = chunk*1024 + lane*16;
      const int r = boff>>7;
      const int cb = (boff&127) ^ ((r&7)<<4);
      gll16(&VT[vbase + (size_t)r*2048 + kv0 + (cb>>1)], &vtls[buf][chunk*512]);
    }
  };

  stage(0, 0);
  __syncthreads();

  for (int kt=0; kt<nkt; ++kt){
    const int kv0 = kt*64;
    const int buf = kt&1;
    if (kt+1 < nkt) stage(buf^1, kt+1);
    f32x4 sacc[4];
#pragma unroll
    for (int n=0;n<4;++n) sacc[n] = f32x4{0.f,0.f,0.f,0.f};
    __builtin_amdgcn_s_setprio(1);
#pragma unroll
    for (int dk=0;dk<4;++dk){
      bf16x8 bk[4];
#pragma unroll
      for (int n=0;n<4;++n){
        const int rb = n*16+lr;
        bk[n] = ldsr8(&kls[buf][(rb*256 + ((dk*64+lg*16) ^ ((rb&7)<<4)))>>1]);
      }
#pragma unroll
      for (int n=0;n<4;++n)
        sacc[n] = mfma16(qf[dk], bk[n], sacc[n]);
    }
    __builtin_amdgcn_s_setprio(0);
#pragma unroll
    for (int n=0;n<4;++n){
      const float madd = (kv0 + n*16 + lr < L) ? 0.f : -1e30f;
#pragma unroll
      for (int r=0;r<4;++r)
        sacc[n][r] = sacc[n][r]*0.0625f + madd;
    }
#pragma unroll
    for (int r=0;r<4;++r){
      float rm = sacc[0][r];
#pragma unroll
      for (int n=1;n<4;++n) rm = fmaxf(rm, sacc[n][r]);
#pragma unroll
      for (int x=1;x<16;x<<=1) rm = fmaxf(rm, __shfl_xor(rm, x));
      const float mnew = fmaxf(mrun[r], rm);
      const float alpha = __expf(mrun[r] - mnew);
      float rsum = 0.f;
#pragma unroll
      for (int n=0;n<4;++n){
        float p = __expf(sacc[n][r] - mnew);
        sacc[n][r] = p;
        rsum += p;
      }
#pragma unroll
      for (int x=1;x<16;x<<=1) rsum += __shfl_xor(rsum, x);
      lrun[r] = alpha*lrun[r] + rsum;
      mrun[r] = mnew;
#pragma unroll
      for (int n=0;n<8;++n) oacc[n][r] *= alpha;
    }
#pragma unroll
    for (int n=0;n<4;++n)
#pragma unroll
      for (int r=0;r<4;++r){
        const int row = lg*4 + r;
        pw[(row*128 + (((n*16+lr)*2) ^ ((row&7)<<4)))>>1] = f2bf(sacc[n][r]);
      }
    __builtin_amdgcn_s_setprio(1);
#pragma unroll
    for (int ks=0;ks<2;++ks){
      bf16x8 pa = ldsr8(&pw[(lr*128 + ((ks*64+lg*16) ^ ((lr&7)<<4)))>>1]);
#pragma unroll
      for (int n=0;n<8;++n){
        const int rv = n*16+lr;
        bf16x8 bvv = ldsr8(&vtls[buf][(rv*128 + ((ks*64+lg*16) ^ ((rv&7)<<4)))>>1]);
        oacc[n] = mfma16(pa, bvv, oacc[n]);
      }
    }
    __builtin_amdgcn_s_setprio(0);
    __syncthreads();
  }
#pragma unroll
  for (int r=0;r<4;++r){
    const float inv = lrun[r] > 0.f ? 1.f/lrun[r] : 0.f;
    const int row = q0 + w*16 + lg*4 + r;
#pragma unroll
    for (int n=0;n<8;++n){
      const int col = hh*128 + n*16 + lr;
      ctx[((size_t)(b*2048+row))*256 + col] = f2bf(oacc[n][r]*inv);
    }
  }
}

extern "C" void kernel_launch(void* const* d_in, const int* in_sizes, int n_in,
                              void* d_out, int out_size, void* d_ws, size_t ws_size,
                              hipStream_t stream)
{
  (void)in_sizes; (void)n_in; (void)out_size; (void)ws_size;
  const float* batch=(const float*)d_in[0];  const void* mraw = d_in[1];
  const float* wq=(const float*)d_in[2];  const float* bq=(const float*)d_in[3];
  const float* wk=(const float*)d_in[4];  const float* bk=(const float*)d_in[5];
  const float* wv=(const float*)d_in[6];  const float* bvv=(const float*)d_in[7];
  const float* wo=(const float*)d_in[8];  const float* bo=(const float*)d_in[9];
  const float* g1=(const float*)d_in[10]; const float* be1=(const float*)d_in[11];
  const float* w1=(const float*)d_in[12]; const float* b1=(const float*)d_in[13];
  const float* w2=(const float*)d_in[14]; const float* b2=(const float*)d_in[15];
  const float* g2=(const float*)d_in[16]; const float* be2=(const float*)d_in[17];

  char* ws = (char*)d_ws;
  const size_t M = 1024u*1024u;
  u16*   batchc = (u16*)(ws);          // 0..8M   (live until outproj_ln residual)
  u16*   q      = (u16*)(ws + 8*M);    // 8..16M  (dead after attn)
  u16*   kbuf   = (u16*)(ws + 16*M);   // 16..24M (dead after attn)
  u16*   v      = (u16*)(ws + 24*M);   // 24..32M (dead after vtrans)
  u16*   ctx    = (u16*)(ws + 32*M);   // 32..40M (dead after outproj_ln)
  u16*   VT     = (u16*)(ws + 40*M);   // 40..48M (over seq1p region; dead after attn)
  u16*   seq1p  = (u16*)(ws + 40*M);   // 40..48.1M padded [8][2056][256]
  u16*   h      = (u16*)(ws);          // 0..32M  (over batchc..v; live conv1..conv2)
  u16*   wqc    = (u16*)(ws + 49*M);
  u16*   woc    = wqc + 196608;
  u16*   w2c    = wqc + 262144;
  u16*   w1r    = (u16*)(ws + 50*M);
  u16*   params = w1r + 2359296;
  u16*   cmask  = params + 4096;
  u32*   lengths= (u32*)(cmask + 16384);

  dim3 blk(256,1,1);
  dim3 blk512(512,1,1);

  prep_big<<<dim3(13824,1,1), blk, 0, stream>>>(batch, wq, wk, wv, wo, w2, w1,
                                                batchc, wqc, w1r);
  prep_small<<<dim3(2,1,1), blk, 0, stream>>>(bq,bk,bvv,bo,g1,be1,g2,be2,b1,b2,
                                              params, mraw, cmask, lengths);

  gemm_qkv<<<dim3(128,6,1), blk, 0, stream>>>(batchc, wqc, params, q, cmask);

  vtrans<<<dim3(256,4,1), blk, 0, stream>>>(v, VT);

  attn_fwd<<<dim3(256,1,1), blk512, 0, stream>>>(q, kbuf, VT, lengths, ctx);

  zero_halo<<<dim3(64,1,1), blk, 0, stream>>>(seq1p);

  outproj_ln<<<dim3(256,1,1), blk512, 0, stream>>>(ctx, woc, params+768, batchc,
                                                   params+1024, params+1280, cmask, seq1p);

  conv1_gemm<<<dim3(128,8,1), blk, 0, stream>>>(seq1p, w1r, params+2048, h, cmask);

  conv2_ln<<<dim3(256,1,1), blk512, 0, stream>>>(h, w2c, params+3072, seq1p,
                                                 params+1536, params+1792, cmask,
                                                 (float*)d_out);
}

// Round 26
// 288.959 us; speedup vs baseline: 1.0761x; 1.0761x over previous
//
#include <hip/hip_runtime.h>

typedef unsigned char  u8;
typedef unsigned short u16;
typedef unsigned int   u32;
typedef __attribute__((ext_vector_type(4))) float f32x4;
typedef __attribute__((ext_vector_type(8))) __bf16 bf16x8;
typedef __attribute__((ext_vector_type(4))) u32  u32x4;
typedef __attribute__((ext_vector_type(2))) u32  u32x2;

__device__ __forceinline__ float bf2f(u16 h){ u32 u = ((u32)h)<<16; return __builtin_bit_cast(float, u); }
__device__ __forceinline__ u16  f2bf(float f){
  u32 u = __builtin_bit_cast(u32, f);
  u32 r = u + 0x7FFFu + ((u>>16)&1u);
  return (u16)(r>>16);
}

typedef const __attribute__((address_space(1))) u32 gas_u32;
typedef __attribute__((address_space(3))) u32 las_u32;
__device__ __forceinline__ void gll16(const void* g, void* l){
  __builtin_amdgcn_global_load_lds((gas_u32*)g, (las_u32*)l, 16, 0, 0);
}

__device__ __forceinline__ f32x4 mfma16(bf16x8 a, bf16x8 b, f32x4 c){
  return __builtin_amdgcn_mfma_f32_16x16x32_bf16(a, b, c, 0, 0, 0);
}

__device__ __forceinline__ bf16x8 ldsr8(const u16* p){
  u32x4 v = *(const u32x4*)p;
  return __builtin_bit_cast(bf16x8, v);
}

// XCD co-locate remap (A-panel-shared GEMMs: same-m blocks on one XCD)
__device__ __forceinline__ void xcd_remap(int &m_idx, int &n_idx){
  const int Mt = gridDim.x;
  const int fid = blockIdx.x + Mt*blockIdx.y;
  const int xcd = fid & 7, k = fid >> 3;
  const int mpx = Mt >> 3;
  m_idx = xcd*mpx + (k % mpx);
  n_idx = k / mpx;
}

// ------- prologue A: batch cvt + weight cvt + conv1 weight repack -------
__global__ __launch_bounds__(256)
void prep_big(const float* __restrict__ batch,
              const float* __restrict__ wq, const float* __restrict__ wk,
              const float* __restrict__ wv, const float* __restrict__ wo,
              const float* __restrict__ w2, const float* __restrict__ w1,
              u16* __restrict__ batchc, u16* __restrict__ wqc, u16* __restrict__ w1r)
{
  const int bid = blockIdx.x, tid = threadIdx.x;
  if (bid < 4096){
    const int i = bid*1024 + tid*4;
    f32x4 v = *(const f32x4*)&batch[i];
    u32x2 o;
    o[0] = (u32)f2bf(v[0]) | ((u32)f2bf(v[1])<<16);
    o[1] = (u32)f2bf(v[2]) | ((u32)f2bf(v[3])<<16);
    *(u32x2*)&batchc[i] = o;
  } else if (bid < 4608){
    const int i = (bid-4096)*1024 + tid*4;
    const float* s; int off;
    if      (i < 65536)  { s = wq; off = i; }
    else if (i < 131072) { s = wk; off = i - 65536; }
    else if (i < 196608) { s = wv; off = i - 131072; }
    else if (i < 262144) { s = wo; off = i - 196608; }
    else                 { s = w2; off = i - 262144; }
    f32x4 v = *(const f32x4*)&s[off];
    u32x2 o;
    o[0] = (u32)f2bf(v[0]) | ((u32)f2bf(v[1])<<16);
    o[1] = (u32)f2bf(v[2]) | ((u32)f2bf(v[3])<<16);
    *(u32x2*)&wqc[i] = o;
  } else {
    const int idx = (bid-4608)*256 + tid;
    const int c = idx / 2304;
    const int t = idx - c*2304;
    const int i = t / 9;
    const int kk = t - i*9;
    w1r[c*2304 + kk*256 + i] = f2bf(w1[idx]);
  }
}

// ------- prologue B: params + mask canon + lengths -------
__global__ __launch_bounds__(256)
void prep_small(const float* p0,const float* p1,const float* p2,const float* p3,
                const float* p4,const float* p5,const float* p6,const float* p7,
                const float* p8,const float* p9,
                u16* __restrict__ params, const void* __restrict__ mraw,
                u16* __restrict__ cmask, u32* __restrict__ lengths)
{
  const int bid = blockIdx.x, tid = threadIdx.x;
  if (bid == 0){
    const float* ps[10] = {p0,p1,p2,p3,p4,p5,p6,p7,p8,p9};
    const int  off[10] = {0,256,512,768,1024,1280,1536,1792,2048,3072};
    const int  len[10] = {256,256,256,256,256,256,256,256,1024,256};
    for (int a=0;a<10;++a)
      for (int i=tid;i<len[a];i+=256)
        params[off[a]+i] = f2bf(ps[a][i]);
  } else {
    const u8*  pb8  = (const u8*)mraw;
    const u16* pb16 = (const u16*)mraw;
    const u32* pb32 = (const u32*)mraw;
    __shared__ int bad8, bad16, nz8, nz16;
    __shared__ int slen[8];
    if (tid==0){ bad8=0; bad16=0; nz8=0; nz16=0; }
    if (tid<8) slen[tid] = 2048;
    __syncthreads();
    for (int i=tid;i<16384;i+=256){
      u8 v = pb8[i]; int row = i & 2047;
      if (v>1) atomicOr(&bad8,1);
      if (v){ atomicOr(&nz8,1); if (row<1024) atomicOr(&bad8,1); }
      if (row>0 && pb8[i-1]==1 && v==0) atomicOr(&bad8,1);
    }
    for (int i=tid;i<8192;i+=256){
      u16 v = pb16[i]; int row = i & 2047;
      if (!(v==0 || v==0x3F80)) atomicOr(&bad16,1);
      if (v){ atomicOr(&nz16,1); if (row<1024) atomicOr(&bad16,1); }
      if (row>0 && pb16[i-1]==0x3F80 && v==0) atomicOr(&bad16,1);
    }
    __syncthreads();
    const int mode = (!bad8 && nz8) ? 1 : ((!bad16 && nz16) ? 2 : 0);
    for (int i=tid;i<16384;i+=256){
      u16 m;
      if (mode==1)      m = pb8[i]  ? 1 : 0;
      else if (mode==2) m = pb16[i] ? 1 : 0;
      else              m = pb32[i] ? 1 : 0;
      cmask[i] = m;
      if (m) atomicMin(&slen[i>>11], i&2047);
    }
    __syncthreads();
    if (tid<8) lengths[tid] = (u32)slen[tid];
  }
}

// ------- zero the 4-row halos of seq1p [8][2056][256] (after VT is dead) -------
__global__ __launch_bounds__(256)
void zero_halo(u16* __restrict__ seq1p)
{
  const int idx = blockIdx.x*256 + threadIdx.x;   // 16384
  const int b = idx>>11, t = idx&2047;
  const int r = t>>8, c = t&255;
  const int row = (r<4) ? r : (2052 + r - 4);
  seq1p[((size_t)b*2056 + row)*256 + c] = 0;
}

// ------- fused QKV GEMM -------
__global__ __launch_bounds__(256)
void gemm_qkv(const u16* __restrict__ A, const u16* __restrict__ W,
              const u16* __restrict__ bias, u16* __restrict__ qbase,
              const u16* __restrict__ cmask)
{
  __shared__ __align__(16) u16 aL[2][4096];
  __shared__ __align__(16) u16 bL[2][4096];
  const int tid = threadIdx.x, lane = tid&63, w = tid>>6;
  const int wm = w>>1, wn = w&1, lr = lane&15, lg = lane>>4;
  int mi, ni; xcd_remap(mi, ni);
  const int m0 = mi*128, n0 = ni*128;
  if (cmask[m0] != 0) return;

  f32x4 acc[4][4];
#pragma unroll
  for (int i=0;i<4;++i)
#pragma unroll
    for (int j=0;j<4;++j) acc[i][j] = f32x4{0.f,0.f,0.f,0.f};

  auto stage = [&](int buf, int kk){
#pragma unroll
    for (int i=0;i<2;++i){
      const int chunk = w*2+i;
      const int boff  = chunk*1024 + lane*16;
      const int r = boff>>6;
      const int cb = (boff&63) ^ (((r>>1)&3)<<4);
      const int c = cb>>1;
      gll16(&A[(size_t)(m0+r)*256 + kk*32 + c], &aL[buf][chunk*512]);
      gll16(&W[(size_t)(n0+r)*256 + kk*32 + c], &bL[buf][chunk*512]);
    }
  };

  stage(0,0);
  __syncthreads();
  for (int kk=0; kk<8; ++kk){
    if (kk+1<8) stage((kk+1)&1, kk+1);
    const u16* ab = aL[kk&1];
    const u16* bb = bL[kk&1];
    bf16x8 af[4], bv[4];
#pragma unroll
    for (int m=0;m<4;++m){
      const int ra = wm*64+m*16+lr;
      af[m] = ldsr8(&ab[(ra*64 + ((lg*16) ^ (((ra>>1)&3)<<4)))>>1]);
    }
#pragma unroll
    for (int n=0;n<4;++n){
      const int rb = wn*64+n*16+lr;
      bv[n] = ldsr8(&bb[(rb*64 + ((lg*16) ^ (((rb>>1)&3)<<4)))>>1]);
    }
#pragma unroll
    for (int m=0;m<4;++m)
#pragma unroll
      for (int n=0;n<4;++n)
        acc[m][n] = mfma16(af[m], bv[n], acc[m][n]);
    __syncthreads();
  }
#pragma unroll
  for (int m=0;m<4;++m)
#pragma unroll
    for (int n=0;n<4;++n)
#pragma unroll
      for (int r=0;r<4;++r){
        const int row = m0 + wm*64 + m*16 + lg*4 + r;
        const int col = n0 + wn*64 + n*16 + lr;
        const int which = col>>8, ch = col&255;
        float v = acc[m][n][r] + bf2f(bias[col]);
        qbase[(size_t)which*4194304 + (size_t)row*256 + ch] = f2bf(v);
      }
}

// ------- conv1: 128x128 tile, 4 waves, launch_bounds(256,4) — best measured config -------
__global__ __launch_bounds__(256, 4)
void conv1_gemm(const u16* __restrict__ Ap, const u16* __restrict__ W1r,
                const u16* __restrict__ b1, u16* __restrict__ Hout,
                const u16* __restrict__ cmask)
{
  __shared__ __align__(16) u16 aL[2][4096];
  __shared__ __align__(16) u16 bL[2][4096];
  const int tid = threadIdx.x, lane = tid&63, w = tid>>6;
  const int wm = w>>1, wn = w&1, lr = lane&15, lg = lane>>4;
  int mi, ni; xcd_remap(mi, ni);
  const int m0 = mi*128, n0 = ni*128;
  if (cmask[m0] != 0) return;
  const int b = m0>>11, s0 = m0&2047;
  const size_t abase = ((size_t)b*2056 + s0)*256;

  f32x4 acc[4][4];
#pragma unroll
  for (int i=0;i<4;++i)
#pragma unroll
    for (int j=0;j<4;++j) acc[i][j] = f32x4{0.f,0.f,0.f,0.f};

  auto stage = [&](int buf, int kk){
    const int tap = kk>>3, ch0 = (kk&7)*32;
#pragma unroll
    for (int i=0;i<2;++i){
      const int chunk = w*2+i;
      const int boff  = chunk*1024 + lane*16;
      const int r = boff>>6;
      const int cb = (boff&63) ^ (((r>>1)&3)<<4);
      const int c = cb>>1;
      gll16(&Ap[abase + (size_t)(tap + r)*256 + ch0 + c], &aL[buf][chunk*512]);
      gll16(&W1r[(size_t)(n0+r)*2304 + kk*32 + c], &bL[buf][chunk*512]);
    }
  };

  stage(0,0);
  __syncthreads();
  for (int kk=0; kk<72; ++kk){
    if (kk+1<72) stage((kk+1)&1, kk+1);
    const u16* ab = aL[kk&1];
    const u16* bb = bL[kk&1];
    bf16x8 af[4], bv[4];
#pragma unroll
    for (int m=0;m<4;++m){
      const int ra = wm*64+m*16+lr;
      af[m] = ldsr8(&ab[(ra*64 + ((lg*16) ^ (((ra>>1)&3)<<4)))>>1]);
    }
#pragma unroll
    for (int n=0;n<4;++n){
      const int rb = wn*64+n*16+lr;
      bv[n] = ldsr8(&bb[(rb*64 + ((lg*16) ^ (((rb>>1)&3)<<4)))>>1]);
    }
#pragma unroll
    for (int m=0;m<4;++m)
#pragma unroll
      for (int n=0;n<4;++n)
        acc[m][n] = mfma16(af[m], bv[n], acc[m][n]);
    __syncthreads();
  }
#pragma unroll
  for (int m=0;m<4;++m)
#pragma unroll
    for (int n=0;n<4;++n)
#pragma unroll
      for (int r=0;r<4;++r){
        const int row = m0 + wm*64 + m*16 + lg*4 + r;
        const int col = n0 + wn*64 + n*16 + lr;
        float v = acc[m][n][r] + bf2f(b1[col]);
        v = v>0.f ? v : 0.f;
        Hout[(size_t)row*1024 + col] = f2bf(v);
      }
}

// ------- fused outproj + residual(batchc) + LayerNorm1 + mask -> seq1p (padded bf16) -------
__global__ __launch_bounds__(512)
void outproj_ln(const u16* __restrict__ Ctx, const u16* __restrict__ woc,
                const u16* __restrict__ bo, const u16* __restrict__ batchc,
                const u16* __restrict__ g1, const u16* __restrict__ be1,
                const u16* __restrict__ cmask, u16* __restrict__ seq1p)
{
  __shared__ __align__(16) u16 aL[2][2048];
  __shared__ __align__(16) u16 bL[2][8192];
  __shared__ float red[2][32][4][2];
  const int tid = threadIdx.x, lane = tid&63, w = tid>>6;
  const int wm = w>>2, wn = w&3, lr = lane&15, lg = lane>>4;
  int mi, ni; xcd_remap(mi, ni); (void)ni;
  const int m0 = mi*64;
  if (cmask[m0] != 0){
    for (int i=tid;i<64*128;i+=512){
      const int rr = i>>7, cc = (i&127)*2;
      const int row = m0 + rr;
      const size_t prow = (size_t)row + (row>>11)*8 + 4;
      *(u32*)&seq1p[prow*256 + cc] = 0u;
    }
    return;
  }

  f32x4 acc[2][4];
#pragma unroll
  for (int i=0;i<2;++i)
#pragma unroll
    for (int j=0;j<4;++j) acc[i][j] = f32x4{0.f,0.f,0.f,0.f};

  auto stage = [&](int buf, int kk){
    if (w < 4){
      const int boff = w*1024 + lane*16;
      const int r = boff>>6;
      const int cb = (boff&63) ^ (((r>>1)&3)<<4);
      gll16(&Ctx[(size_t)(m0+r)*256 + kk*32 + (cb>>1)], &aL[buf][w*512]);
    }
#pragma unroll
    for (int i=0;i<2;++i){
      const int chunk = w*2+i;
      const int boff = chunk*1024 + lane*16;
      const int r = boff>>6;
      const int cb = (boff&63) ^ (((r>>1)&3)<<4);
      gll16(&woc[(size_t)r*256 + kk*32 + (cb>>1)], &bL[buf][chunk*512]);
    }
  };

  stage(0,0);
  __syncthreads();
  for (int kk=0; kk<8; ++kk){
    if (kk+1<8) stage((kk+1)&1, kk+1);
    const u16* ab = aL[kk&1];
    const u16* bb = bL[kk&1];
    bf16x8 af[2], bv[4];
#pragma unroll
    for (int m=0;m<2;++m){
      const int ra = wm*32+m*16+lr;
      af[m] = ldsr8(&ab[(ra*64 + ((lg*16) ^ (((ra>>1)&3)<<4)))>>1]);
    }
#pragma unroll
    for (int n=0;n<4;++n){
      const int rb = wn*64+n*16+lr;
      bv[n] = ldsr8(&bb[(rb*64 + ((lg*16) ^ (((rb>>1)&3)<<4)))>>1]);
    }
#pragma unroll
    for (int m=0;m<2;++m)
#pragma unroll
      for (int n=0;n<4;++n)
        acc[m][n] = mfma16(af[m], bv[n], acc[m][n]);
    __syncthreads();
  }
#pragma unroll
  for (int m=0;m<2;++m)
#pragma unroll
    for (int r=0;r<4;++r){
      float s = 0.f, qq = 0.f;
#pragma unroll
      for (int n=0;n<4;++n){
        const int col = wn*64 + n*16 + lr;
        const int row = m0 + wm*32 + m*16 + lg*4 + r;
        float val = acc[m][n][r] + bf2f(bo[col]) + bf2f(batchc[(size_t)row*256 + col]);
        acc[m][n][r] = val;
        s += val; qq += val*val;
      }
#pragma unroll
      for (int x=1;x<16;x<<=1){ s += __shfl_xor(s, x); qq += __shfl_xor(qq, x); }
      if (lr == 0){
        const int lrow = m*16 + lg*4 + r;
        red[wm][lrow][wn][0] = s;
        red[wm][lrow][wn][1] = qq;
      }
    }
  __syncthreads();
#pragma unroll
  for (int m=0;m<2;++m)
#pragma unroll
    for (int r=0;r<4;++r){
      const int lrow = m*16 + lg*4 + r;
      const float S = red[wm][lrow][0][0]+red[wm][lrow][1][0]+red[wm][lrow][2][0]+red[wm][lrow][3][0];
      const float Q = red[wm][lrow][0][1]+red[wm][lrow][1][1]+red[wm][lrow][2][1]+red[wm][lrow][3][1];
      const float mu = S*(1.f/256.f);
      const float rs = rsqrtf(Q*(1.f/256.f) - mu*mu + 1e-5f);
      const int row = m0 + wm*32 + lrow;
      const int msk = cmask[row];
      const size_t prow = (size_t)row + (row>>11)*8 + 4;
#pragma unroll
      for (int n=0;n<4;++n){
        const int col = wn*64 + n*16 + lr;
        float y = (acc[m][n][r]-mu)*rs*bf2f(g1[col]) + bf2f(be1[col]);
        seq1p[prow*256 + col] = msk ? (u16)0 : f2bf(y);
      }
    }
}

// ------- fused conv2 + residual + LayerNorm2 + mask (f32 out) -------
__global__ __launch_bounds__(512)
void conv2_ln(const u16* __restrict__ Hh, const u16* __restrict__ w2c,
              const u16* __restrict__ b2, const u16* __restrict__ seq1p,
              const u16* __restrict__ g2, const u16* __restrict__ be2,
              const u16* __restrict__ cmask, float* __restrict__ out)
{
  __shared__ __align__(16) u16 aL[2][2048];
  __shared__ __align__(16) u16 bL[2][8192];
  __shared__ float red[2][32][4][2];
  const int tid = threadIdx.x, lane = tid&63, w = tid>>6;
  const int wm = w>>2, wn = w&3, lr = lane&15, lg = lane>>4;
  int mi, ni; xcd_remap(mi, ni); (void)ni;
  const int m0 = mi*64;
  if (cmask[m0] != 0) return;

  f32x4 acc[2][4];
#pragma unroll
  for (int i=0;i<2;++i)
#pragma unroll
    for (int j=0;j<4;++j) acc[i][j] = f32x4{0.f,0.f,0.f,0.f};

  auto stage = [&](int buf, int kk){
    if (w < 4){
      const int boff = w*1024 + lane*16;
      const int r = boff>>6;
      const int cb = (boff&63) ^ (((r>>1)&3)<<4);
      gll16(&Hh[(size_t)(m0+r)*1024 + kk*32 + (cb>>1)], &aL[buf][w*512]);
    }
#pragma unroll
    for (int i=0;i<2;++i){
      const int chunk = w*2+i;
      const int boff = chunk*1024 + lane*16;
      const int r = boff>>6;
      const int cb = (boff&63) ^ (((r>>1)&3)<<4);
      gll16(&w2c[(size_t)r*1024 + kk*32 + (cb>>1)], &bL[buf][chunk*512]);
    }
  };

  stage(0,0);
  __syncthreads();
  for (int kk=0; kk<32; ++kk){
    if (kk+1<32) stage((kk+1)&1, kk+1);
    const u16* ab = aL[kk&1];
    const u16* bb = bL[kk&1];
    bf16x8 af[2], bv[4];
#pragma unroll
    for (int m=0;m<2;++m){
      const int ra = wm*32+m*16+lr;
      af[m] = ldsr8(&ab[(ra*64 + ((lg*16) ^ (((ra>>1)&3)<<4)))>>1]);
    }
#pragma unroll
    for (int n=0;n<4;++n){
      const int rb = wn*64+n*16+lr;
      bv[n] = ldsr8(&bb[(rb*64 + ((lg*16) ^ (((rb>>1)&3)<<4)))>>1]);
    }
#pragma unroll
    for (int m=0;m<2;++m)
#pragma unroll
      for (int n=0;n<4;++n)
        acc[m][n] = mfma16(af[m], bv[n], acc[m][n]);
    __syncthreads();
  }
#pragma unroll
  for (int m=0;m<2;++m)
#pragma unroll
    for (int r=0;r<4;++r){
      float s = 0.f, qq = 0.f;
#pragma unroll
      for (int n=0;n<4;++n){
        const int col = wn*64 + n*16 + lr;
        const int row = m0 + wm*32 + m*16 + lg*4 + r;
        const size_t ri = ((size_t)row + (row>>11)*8 + 4)*256 + col;
        float val = acc[m][n][r] + bf2f(b2[col]) + bf2f(seq1p[ri]);
        acc[m][n][r] = val;
        s += val; qq += val*val;
      }
#pragma unroll
      for (int x=1;x<16;x<<=1){ s += __shfl_xor(s, x); qq += __shfl_xor(qq, x); }
      if (lr == 0){
        const int lrow = m*16 + lg*4 + r;
        red[wm][lrow][wn][0] = s;
        red[wm][lrow][wn][1] = qq;
      }
    }
  __syncthreads();
#pragma unroll
  for (int m=0;m<2;++m)
#pragma unroll
    for (int r=0;r<4;++r){
      const int lrow = m*16 + lg*4 + r;
      const float S = red[wm][lrow][0][0]+red[wm][lrow][1][0]+red[wm][lrow][2][0]+red[wm][lrow][3][0];
      const float Q = red[wm][lrow][0][1]+red[wm][lrow][1][1]+red[wm][lrow][2][1]+red[wm][lrow][3][1];
      const float mu = S*(1.f/256.f);
      const float rs = rsqrtf(Q*(1.f/256.f) - mu*mu + 1e-5f);
      const int row = m0 + wm*32 + lrow;
      const int msk = cmask[row];
#pragma unroll
      for (int n=0;n<4;++n){
        const int col = wn*64 + n*16 + lr;
        float y = (acc[m][n][r]-mu)*rs*bf2f(g2[col]) + bf2f(be2[col]);
        out[(size_t)row*256 + col] = msk ? 0.f : y;
      }
    }
}

// ------- V [16384][256] -> VT [b][h][128][2048] -------
__global__ __launch_bounds__(256)
void vtrans(const u16* __restrict__ V, u16* __restrict__ VT)
{
  __shared__ u16 t[64][72];
  const int tid = threadIdx.x;
  const int s0 = blockIdx.x*64;
  const int d0 = blockIdx.y*64;
#pragma unroll
  for (int i=0;i<2;++i){
    const int chunk = tid + i*256;
    const int sr = chunk>>3, c8 = (chunk&7)*8;
    u32x4 raw = *(const u32x4*)&V[(size_t)(s0+sr)*256 + d0 + c8];
#pragma unroll
    for (int j=0;j<4;++j){
      t[sr][c8+2*j]   = (u16)(raw[j]&0xffffu);
      t[sr][c8+2*j+1] = (u16)(raw[j]>>16);
    }
  }
  __syncthreads();
  const int b = s0>>11;
#pragma unroll
  for (int i=0;i<2;++i){
    const int chunk = tid + i*256;
    const int dr = chunk>>3, s8 = (chunk&7)*8;
    const int dg = d0 + dr;
    const int hh = dg>>7, dh = dg&127;
    u32x4 o;
#pragma unroll
    for (int j=0;j<4;++j)
      o[j] = (u32)t[s8+2*j][dr] | ((u32)t[s8+2*j+1][dr]<<16);
    *(u32x4*)&VT[((size_t)((b*2+hh)*128 + dh))*2048 + (s0&2047) + s8] = o;
  }
}

// ------- flash attention: q-tile 128, 8 waves, KVBLK=64, dbuf gll16, 1 barrier/tile -------
__global__ __launch_bounds__(512)
void attn_fwd(const u16* __restrict__ Q, const u16* __restrict__ Kb,
              const u16* __restrict__ VT, const u32* __restrict__ lengths,
              u16* __restrict__ ctx)
{
  __shared__ __align__(16) u16 kls[2][64*128];
  __shared__ __align__(16) u16 vtls[2][128*64];
  __shared__ __align__(16) u16 pls[8][16*64];
  const int tid = threadIdx.x, lane = tid&63, w = tid>>6;
  const int fid = blockIdx.x;
  const int pair = fid & 15;
  const int qt = fid >> 4;
  const int b  = pair >> 1;
  const int hh = pair & 1;
  const int q0 = qt*128;
  const int L  = (int)lengths[b];
  if (q0 >= L) return;
  const int nkt = (L + 63) >> 6;
  const int lr = lane&15, lg = lane>>4;
  u16* pw = pls[w];

  bf16x8 qf[4];
#pragma unroll
  for (int d=0;d<4;++d)
    qf[d] = *(const bf16x8*)&Q[((size_t)(b*2048+q0+w*16+lr))*256 + hh*128 + d*32 + lg*8];

  f32x4 oacc[8];
  float mrun[4], lrun[4];
#pragma unroll
  for (int n=0;n<8;++n) oacc[n] = f32x4{0.f,0.f,0.f,0.f};
#pragma unroll
  for (int r=0;r<4;++r){ mrun[r] = -1e30f; lrun[r] = 0.f; }

  const size_t kbase = (size_t)(b*2048)*256 + hh*128;
  const size_t vbase = (size_t)((b*2+hh)*128)*2048;

  auto stage = [&](int buf, int kt){
    const int kv0 = kt*64;
#pragma unroll
    for (int i=0;i<2;++i){
      const int chunk = w*2+i;
      const int boff = chunk*1024 + lane*16;
      const int r = boff>>8;
      const int cb = (boff&255) ^ ((r&7)<<4);
      gll16(&Kb[kbase + (size_t)(kv0+r)*256 + (cb>>1)], &kls[buf][chunk*512]);
    }
#pragma unroll
    for (int i=0;i<2;++i){
      const int chunk = w*2+i;
      const int boff = chunk*1024 + lane*16;
      const int r = boff>>7;
      const int cb = (boff&127) ^ ((r&7)<<4);
      gll16(&VT[vbase + (size_t)r*2048 + kv0 + (cb>>1)], &vtls[buf][chunk*512]);
    }
  };

  stage(0, 0);
  __syncthreads();

  for (int kt=0; kt<nkt; ++kt){
    const int kv0 = kt*64;
    const int buf = kt&1;
    if (kt+1 < nkt) stage(buf^1, kt+1);
    f32x4 sacc[4];
#pragma unroll
    for (int n=0;n<4;++n) sacc[n] = f32x4{0.f,0.f,0.f,0.f};
    __builtin_amdgcn_s_setprio(1);
#pragma unroll
    for (int dk=0;dk<4;++dk){
      bf16x8 bk[4];
#pragma unroll
      for (int n=0;n<4;++n){
        const int rb = n*16+lr;
        bk[n] = ldsr8(&kls[buf][(rb*256 + ((dk*64+lg*16) ^ ((rb&7)<<4)))>>1]);
      }
#pragma unroll
      for (int n=0;n<4;++n)
        sacc[n] = mfma16(qf[dk], bk[n], sacc[n]);
    }
    __builtin_amdgcn_s_setprio(0);
#pragma unroll
    for (int n=0;n<4;++n){
      const float madd = (kv0 + n*16 + lr < L) ? 0.f : -1e30f;
#pragma unroll
      for (int r=0;r<4;++r)
        sacc[n][r] = sacc[n][r]*0.0625f + madd;
    }
#pragma unroll
    for (int r=0;r<4;++r){
      float rm = sacc[0][r];
#pragma unroll
      for (int n=1;n<4;++n) rm = fmaxf(rm, sacc[n][r]);
#pragma unroll
      for (int x=1;x<16;x<<=1) rm = fmaxf(rm, __shfl_xor(rm, x));
      const float mnew = fmaxf(mrun[r], rm);
      const float alpha = __expf(mrun[r] - mnew);
      float rsum = 0.f;
#pragma unroll
      for (int n=0;n<4;++n){
        float p = __expf(sacc[n][r] - mnew);
        sacc[n][r] = p;
        rsum += p;
      }
#pragma unroll
      for (int x=1;x<16;x<<=1) rsum += __shfl_xor(rsum, x);
      lrun[r] = alpha*lrun[r] + rsum;
      mrun[r] = mnew;
#pragma unroll
      for (int n=0;n<8;++n) oacc[n][r] *= alpha;
    }
#pragma unroll
    for (int n=0;n<4;++n)
#pragma unroll
      for (int r=0;r<4;++r){
        const int row = lg*4 + r;
        pw[(row*128 + (((n*16+lr)*2) ^ ((row&7)<<4)))>>1] = f2bf(sacc[n][r]);
      }
    __builtin_amdgcn_s_setprio(1);
#pragma unroll
    for (int ks=0;ks<2;++ks){
      bf16x8 pa = ldsr8(&pw[(lr*128 + ((ks*64+lg*16) ^ ((lr&7)<<4)))>>1]);
#pragma unroll
      for (int n=0;n<8;++n){
        const int rv = n*16+lr;
        bf16x8 bvv = ldsr8(&vtls[buf][(rv*128 + ((ks*64+lg*16) ^ ((rv&7)<<4)))>>1]);
        oacc[n] = mfma16(pa, bvv, oacc[n]);
      }
    }
    __builtin_amdgcn_s_setprio(0);
    __syncthreads();
  }
#pragma unroll
  for (int r=0;r<4;++r){
    const float inv = lrun[r] > 0.f ? 1.f/lrun[r] : 0.f;
    const int row = q0 + w*16 + lg*4 + r;
#pragma unroll
    for (int n=0;n<8;++n){
      const int col = hh*128 + n*16 + lr;
      ctx[((size_t)(b*2048+row))*256 + col] = f2bf(oacc[n][r]*inv);
    }
  }
}

extern "C" void kernel_launch(void* const* d_in, const int* in_sizes, int n_in,
                              void* d_out, int out_size, void* d_ws, size_t ws_size,
                              hipStream_t stream)
{
  (void)in_sizes; (void)n_in; (void)out_size; (void)ws_size;
  const float* batch=(const float*)d_in[0];  const void* mraw = d_in[1];
  const float* wq=(const float*)d_in[2];  const float* bq=(const float*)d_in[3];
  const float* wk=(const float*)d_in[4];  const float* bk=(const float*)d_in[5];
  const float* wv=(const float*)d_in[6];  const float* bvv=(const float*)d_in[7];
  const float* wo=(const float*)d_in[8];  const float* bo=(const float*)d_in[9];
  const float* g1=(const float*)d_in[10]; const float* be1=(const float*)d_in[11];
  const float* w1=(const float*)d_in[12]; const float* b1=(const float*)d_in[13];
  const float* w2=(const float*)d_in[14]; const float* b2=(const float*)d_in[15];
  const float* g2=(const float*)d_in[16]; const float* be2=(const float*)d_in[17];

  char* ws = (char*)d_ws;
  const size_t M = 1024u*1024u;
  u16*   batchc = (u16*)(ws);          // 0..8M   (live until outproj_ln residual)
  u16*   q      = (u16*)(ws + 8*M);    // 8..16M  (dead after attn)
  u16*   kbuf   = (u16*)(ws + 16*M);   // 16..24M (dead after attn)
  u16*   v      = (u16*)(ws + 24*M);   // 24..32M (dead after vtrans)
  u16*   ctx    = (u16*)(ws + 32*M);   // 32..40M (dead after outproj_ln)
  u16*   VT     = (u16*)(ws + 40*M);   // 40..48M (over seq1p region; dead after attn)
  u16*   seq1p  = (u16*)(ws + 40*M);   // 40..48.1M padded [8][2056][256]
  u16*   h      = (u16*)(ws);          // 0..32M  (over batchc..v; live conv1..conv2)
  u16*   wqc    = (u16*)(ws + 49*M);
  u16*   woc    = wqc + 196608;
  u16*   w2c    = wqc + 262144;
  u16*   w1r    = (u16*)(ws + 50*M);
  u16*   params = w1r + 2359296;
  u16*   cmask  = params + 4096;
  u32*   lengths= (u32*)(cmask + 16384);

  dim3 blk(256,1,1);
  dim3 blk512(512,1,1);

  prep_big<<<dim3(13824,1,1), blk, 0, stream>>>(batch, wq, wk, wv, wo, w2, w1,
                                                batchc, wqc, w1r);
  prep_small<<<dim3(2,1,1), blk, 0, stream>>>(bq,bk,bvv,bo,g1,be1,g2,be2,b1,b2,
                                              params, mraw, cmask, lengths);

  gemm_qkv<<<dim3(128,6,1), blk, 0, stream>>>(batchc, wqc, params, q, cmask);

  vtrans<<<dim3(256,4,1), blk, 0, stream>>>(v, VT);

  attn_fwd<<<dim3(256,1,1), blk512, 0, stream>>>(q, kbuf, VT, lengths, ctx);

  zero_halo<<<dim3(64,1,1), blk, 0, stream>>>(seq1p);

  outproj_ln<<<dim3(256,1,1), blk512, 0, stream>>>(ctx, woc, params+768, batchc,
                                                   params+1024, params+1280, cmask, seq1p);

  conv1_gemm<<<dim3(128,8,1), blk, 0, stream>>>(seq1p, w1r, params+2048, h, cmask);

  conv2_ln<<<dim3(256,1,1), blk512, 0, stream>>>(h, w2c, params+3072, seq1p,
                                                 params+1536, params+1792, cmask,
                                                 (float*)d_out);
}

// Round 27
// 288.130 us; speedup vs baseline: 1.0792x; 1.0029x over previous
//
#include <hip/hip_runtime.h>

typedef unsigned char  u8;
typedef unsigned short u16;
typedef unsigned int   u32;
typedef __attribute__((ext_vector_type(4))) float f32x4;
typedef __attribute__((ext_vector_type(8))) __bf16 bf16x8;
typedef __attribute__((ext_vector_type(4))) u32  u32x4;
typedef __attribute__((ext_vector_type(2))) u32  u32x2;

__device__ __forceinline__ float bf2f(u16 h){ u32 u = ((u32)h)<<16; return __builtin_bit_cast(float, u); }
__device__ __forceinline__ u16  f2bf(float f){
  u32 u = __builtin_bit_cast(u32, f);
  u32 r = u + 0x7FFFu + ((u>>16)&1u);
  return (u16)(r>>16);
}

typedef const __attribute__((address_space(1))) u32 gas_u32;
typedef __attribute__((address_space(3))) u32 las_u32;
__device__ __forceinline__ void gll16(const void* g, void* l){
  __builtin_amdgcn_global_load_lds((gas_u32*)g, (las_u32*)l, 16, 0, 0);
}

__device__ __forceinline__ f32x4 mfma16(bf16x8 a, bf16x8 b, f32x4 c){
  return __builtin_amdgcn_mfma_f32_16x16x32_bf16(a, b, c, 0, 0, 0);
}

__device__ __forceinline__ bf16x8 ldsr8(const u16* p){
  u32x4 v = *(const u32x4*)p;
  return __builtin_bit_cast(bf16x8, v);
}

// batch-balanced XCD remap: m-tile g = b*TPB + t lands on XCD (t+b)&7 (rotated stripe).
// - all n-blocks of a given m-tile share one XCD (A-panel L2 locality preserved)
// - each XCD gets TPB/8 tiles from EVERY batch; per-batch live residuals rotate
//   across XCDs -> live work equalized despite variable lengths.
// TPB = m-tiles per batch (16 for 128-row tiles, 32 for 64-row tiles).
__device__ __forceinline__ void xcd_remap_bal(int TPB, int &m_idx, int &n_idx){
  const int Mt = gridDim.x;
  const int fid = blockIdx.x + Mt*blockIdx.y;
  const int xcd = fid & 7, k = fid >> 3;
  const int j  = k % TPB;
  n_idx = k / TPB;
  const int b  = j & 7;
  const int hi = j >> 3;
  const int t  = ((xcd - b) & 7) + hi*8;
  m_idx = b*TPB + t;
}

// ------- prologue A: batch cvt + weight cvt + conv1 weight repack -------
__global__ __launch_bounds__(256)
void prep_big(const float* __restrict__ batch,
              const float* __restrict__ wq, const float* __restrict__ wk,
              const float* __restrict__ wv, const float* __restrict__ wo,
              const float* __restrict__ w2, const float* __restrict__ w1,
              u16* __restrict__ batchc, u16* __restrict__ wqc, u16* __restrict__ w1r)
{
  const int bid = blockIdx.x, tid = threadIdx.x;
  if (bid < 4096){
    const int i = bid*1024 + tid*4;
    f32x4 v = *(const f32x4*)&batch[i];
    u32x2 o;
    o[0] = (u32)f2bf(v[0]) | ((u32)f2bf(v[1])<<16);
    o[1] = (u32)f2bf(v[2]) | ((u32)f2bf(v[3])<<16);
    *(u32x2*)&batchc[i] = o;
  } else if (bid < 4608){
    const int i = (bid-4096)*1024 + tid*4;
    const float* s; int off;
    if      (i < 65536)  { s = wq; off = i; }
    else if (i < 131072) { s = wk; off = i - 65536; }
    else if (i < 196608) { s = wv; off = i - 131072; }
    else if (i < 262144) { s = wo; off = i - 196608; }
    else                 { s = w2; off = i - 262144; }
    f32x4 v = *(const f32x4*)&s[off];
    u32x2 o;
    o[0] = (u32)f2bf(v[0]) | ((u32)f2bf(v[1])<<16);
    o[1] = (u32)f2bf(v[2]) | ((u32)f2bf(v[3])<<16);
    *(u32x2*)&wqc[i] = o;
  } else {
    const int idx = (bid-4608)*256 + tid;
    const int c = idx / 2304;
    const int t = idx - c*2304;
    const int i = t / 9;
    const int kk = t - i*9;
    w1r[c*2304 + kk*256 + i] = f2bf(w1[idx]);
  }
}

// ------- prologue B: params + mask canon + lengths -------
__global__ __launch_bounds__(256)
void prep_small(const float* p0,const float* p1,const float* p2,const float* p3,
                const float* p4,const float* p5,const float* p6,const float* p7,
                const float* p8,const float* p9,
                u16* __restrict__ params, const void* __restrict__ mraw,
                u16* __restrict__ cmask, u32* __restrict__ lengths)
{
  const int bid = blockIdx.x, tid = threadIdx.x;
  if (bid == 0){
    const float* ps[10] = {p0,p1,p2,p3,p4,p5,p6,p7,p8,p9};
    const int  off[10] = {0,256,512,768,1024,1280,1536,1792,2048,3072};
    const int  len[10] = {256,256,256,256,256,256,256,256,1024,256};
    for (int a=0;a<10;++a)
      for (int i=tid;i<len[a];i+=256)
        params[off[a]+i] = f2bf(ps[a][i]);
  } else {
    const u8*  pb8  = (const u8*)mraw;
    const u16* pb16 = (const u16*)mraw;
    const u32* pb32 = (const u32*)mraw;
    __shared__ int bad8, bad16, nz8, nz16;
    __shared__ int slen[8];
    if (tid==0){ bad8=0; bad16=0; nz8=0; nz16=0; }
    if (tid<8) slen[tid] = 2048;
    __syncthreads();
    for (int i=tid;i<16384;i+=256){
      u8 v = pb8[i]; int row = i & 2047;
      if (v>1) atomicOr(&bad8,1);
      if (v){ atomicOr(&nz8,1); if (row<1024) atomicOr(&bad8,1); }
      if (row>0 && pb8[i-1]==1 && v==0) atomicOr(&bad8,1);
    }
    for (int i=tid;i<8192;i+=256){
      u16 v = pb16[i]; int row = i & 2047;
      if (!(v==0 || v==0x3F80)) atomicOr(&bad16,1);
      if (v){ atomicOr(&nz16,1); if (row<1024) atomicOr(&bad16,1); }
      if (row>0 && pb16[i-1]==0x3F80 && v==0) atomicOr(&bad16,1);
    }
    __syncthreads();
    const int mode = (!bad8 && nz8) ? 1 : ((!bad16 && nz16) ? 2 : 0);
    for (int i=tid;i<16384;i+=256){
      u16 m;
      if (mode==1)      m = pb8[i]  ? 1 : 0;
      else if (mode==2) m = pb16[i] ? 1 : 0;
      else              m = pb32[i] ? 1 : 0;
      cmask[i] = m;
      if (m) atomicMin(&slen[i>>11], i&2047);
    }
    __syncthreads();
    if (tid<8) lengths[tid] = (u32)slen[tid];
  }
}

// ------- zero the 4-row halos of seq1p [8][2056][256] (after VT is dead) -------
__global__ __launch_bounds__(256)
void zero_halo(u16* __restrict__ seq1p)
{
  const int idx = blockIdx.x*256 + threadIdx.x;   // 16384
  const int b = idx>>11, t = idx&2047;
  const int r = t>>8, c = t&255;
  const int row = (r<4) ? r : (2052 + r - 4);
  seq1p[((size_t)b*2056 + row)*256 + c] = 0;
}

// ------- fused QKV GEMM -------
__global__ __launch_bounds__(256)
void gemm_qkv(const u16* __restrict__ A, const u16* __restrict__ W,
              const u16* __restrict__ bias, u16* __restrict__ qbase,
              const u16* __restrict__ cmask)
{
  __shared__ __align__(16) u16 aL[2][4096];
  __shared__ __align__(16) u16 bL[2][4096];
  const int tid = threadIdx.x, lane = tid&63, w = tid>>6;
  const int wm = w>>1, wn = w&1, lr = lane&15, lg = lane>>4;
  int mi, ni; xcd_remap_bal(16, mi, ni);
  const int m0 = mi*128, n0 = ni*128;
  if (cmask[m0] != 0) return;

  f32x4 acc[4][4];
#pragma unroll
  for (int i=0;i<4;++i)
#pragma unroll
    for (int j=0;j<4;++j) acc[i][j] = f32x4{0.f,0.f,0.f,0.f};

  auto stage = [&](int buf, int kk){
#pragma unroll
    for (int i=0;i<2;++i){
      const int chunk = w*2+i;
      const int boff  = chunk*1024 + lane*16;
      const int r = boff>>6;
      const int cb = (boff&63) ^ (((r>>1)&3)<<4);
      const int c = cb>>1;
      gll16(&A[(size_t)(m0+r)*256 + kk*32 + c], &aL[buf][chunk*512]);
      gll16(&W[(size_t)(n0+r)*256 + kk*32 + c], &bL[buf][chunk*512]);
    }
  };

  stage(0,0);
  __syncthreads();
  for (int kk=0; kk<8; ++kk){
    if (kk+1<8) stage((kk+1)&1, kk+1);
    const u16* ab = aL[kk&1];
    const u16* bb = bL[kk&1];
    bf16x8 af[4], bv[4];
#pragma unroll
    for (int m=0;m<4;++m){
      const int ra = wm*64+m*16+lr;
      af[m] = ldsr8(&ab[(ra*64 + ((lg*16) ^ (((ra>>1)&3)<<4)))>>1]);
    }
#pragma unroll
    for (int n=0;n<4;++n){
      const int rb = wn*64+n*16+lr;
      bv[n] = ldsr8(&bb[(rb*64 + ((lg*16) ^ (((rb>>1)&3)<<4)))>>1]);
    }
#pragma unroll
    for (int m=0;m<4;++m)
#pragma unroll
      for (int n=0;n<4;++n)
        acc[m][n] = mfma16(af[m], bv[n], acc[m][n]);
    __syncthreads();
  }
#pragma unroll
  for (int m=0;m<4;++m)
#pragma unroll
    for (int n=0;n<4;++n)
#pragma unroll
      for (int r=0;r<4;++r){
        const int row = m0 + wm*64 + m*16 + lg*4 + r;
        const int col = n0 + wn*64 + n*16 + lr;
        const int which = col>>8, ch = col&255;
        float v = acc[m][n][r] + bf2f(bias[col]);
        qbase[(size_t)which*4194304 + (size_t)row*256 + ch] = f2bf(v);
      }
}

// ------- conv1: 128x128 tile, 4 waves, launch_bounds(256,4), balanced XCD stripe -------
__global__ __launch_bounds__(256, 4)
void conv1_gemm(const u16* __restrict__ Ap, const u16* __restrict__ W1r,
                const u16* __restrict__ b1, u16* __restrict__ Hout,
                const u16* __restrict__ cmask)
{
  __shared__ __align__(16) u16 aL[2][4096];
  __shared__ __align__(16) u16 bL[2][4096];
  const int tid = threadIdx.x, lane = tid&63, w = tid>>6;
  const int wm = w>>1, wn = w&1, lr = lane&15, lg = lane>>4;
  int mi, ni; xcd_remap_bal(16, mi, ni);
  const int m0 = mi*128, n0 = ni*128;
  if (cmask[m0] != 0) return;
  const int b = m0>>11, s0 = m0&2047;
  const size_t abase = ((size_t)b*2056 + s0)*256;

  f32x4 acc[4][4];
#pragma unroll
  for (int i=0;i<4;++i)
#pragma unroll
    for (int j=0;j<4;++j) acc[i][j] = f32x4{0.f,0.f,0.f,0.f};

  auto stage = [&](int buf, int kk){
    const int tap = kk>>3, ch0 = (kk&7)*32;
#pragma unroll
    for (int i=0;i<2;++i){
      const int chunk = w*2+i;
      const int boff  = chunk*1024 + lane*16;
      const int r = boff>>6;
      const int cb = (boff&63) ^ (((r>>1)&3)<<4);
      const int c = cb>>1;
      gll16(&Ap[abase + (size_t)(tap + r)*256 + ch0 + c], &aL[buf][chunk*512]);
      gll16(&W1r[(size_t)(n0+r)*2304 + kk*32 + c], &bL[buf][chunk*512]);
    }
  };

  stage(0,0);
  __syncthreads();
  for (int kk=0; kk<72; ++kk){
    if (kk+1<72) stage((kk+1)&1, kk+1);
    const u16* ab = aL[kk&1];
    const u16* bb = bL[kk&1];
    bf16x8 af[4], bv[4];
#pragma unroll
    for (int m=0;m<4;++m){
      const int ra = wm*64+m*16+lr;
      af[m] = ldsr8(&ab[(ra*64 + ((lg*16) ^ (((ra>>1)&3)<<4)))>>1]);
    }
#pragma unroll
    for (int n=0;n<4;++n){
      const int rb = wn*64+n*16+lr;
      bv[n] = ldsr8(&bb[(rb*64 + ((lg*16) ^ (((rb>>1)&3)<<4)))>>1]);
    }
#pragma unroll
    for (int m=0;m<4;++m)
#pragma unroll
      for (int n=0;n<4;++n)
        acc[m][n] = mfma16(af[m], bv[n], acc[m][n]);
    __syncthreads();
  }
#pragma unroll
  for (int m=0;m<4;++m)
#pragma unroll
    for (int n=0;n<4;++n)
#pragma unroll
      for (int r=0;r<4;++r){
        const int row = m0 + wm*64 + m*16 + lg*4 + r;
        const int col = n0 + wn*64 + n*16 + lr;
        float v = acc[m][n][r] + bf2f(b1[col]);
        v = v>0.f ? v : 0.f;
        Hout[(size_t)row*1024 + col] = f2bf(v);
      }
}

// ------- fused outproj + residual(batchc) + LayerNorm1 + mask -> seq1p (padded bf16) -------
__global__ __launch_bounds__(512)
void outproj_ln(const u16* __restrict__ Ctx, const u16* __restrict__ woc,
                const u16* __restrict__ bo, const u16* __restrict__ batchc,
                const u16* __restrict__ g1, const u16* __restrict__ be1,
                const u16* __restrict__ cmask, u16* __restrict__ seq1p)
{
  __shared__ __align__(16) u16 aL[2][2048];
  __shared__ __align__(16) u16 bL[2][8192];
  __shared__ float red[2][32][4][2];
  const int tid = threadIdx.x, lane = tid&63, w = tid>>6;
  const int wm = w>>2, wn = w&3, lr = lane&15, lg = lane>>4;
  int mi, ni; xcd_remap_bal(32, mi, ni); (void)ni;
  const int m0 = mi*64;
  if (cmask[m0] != 0){
    for (int i=tid;i<64*128;i+=512){
      const int rr = i>>7, cc = (i&127)*2;
      const int row = m0 + rr;
      const size_t prow = (size_t)row + (row>>11)*8 + 4;
      *(u32*)&seq1p[prow*256 + cc] = 0u;
    }
    return;
  }

  f32x4 acc[2][4];
#pragma unroll
  for (int i=0;i<2;++i)
#pragma unroll
    for (int j=0;j<4;++j) acc[i][j] = f32x4{0.f,0.f,0.f,0.f};

  auto stage = [&](int buf, int kk){
    if (w < 4){
      const int boff = w*1024 + lane*16;
      const int r = boff>>6;
      const int cb = (boff&63) ^ (((r>>1)&3)<<4);
      gll16(&Ctx[(size_t)(m0+r)*256 + kk*32 + (cb>>1)], &aL[buf][w*512]);
    }
#pragma unroll
    for (int i=0;i<2;++i){
      const int chunk = w*2+i;
      const int boff = chunk*1024 + lane*16;
      const int r = boff>>6;
      const int cb = (boff&63) ^ (((r>>1)&3)<<4);
      gll16(&woc[(size_t)r*256 + kk*32 + (cb>>1)], &bL[buf][chunk*512]);
    }
  };

  stage(0,0);
  __syncthreads();
  for (int kk=0; kk<8; ++kk){
    if (kk+1<8) stage((kk+1)&1, kk+1);
    const u16* ab = aL[kk&1];
    const u16* bb = bL[kk&1];
    bf16x8 af[2], bv[4];
#pragma unroll
    for (int m=0;m<2;++m){
      const int ra = wm*32+m*16+lr;
      af[m] = ldsr8(&ab[(ra*64 + ((lg*16) ^ (((ra>>1)&3)<<4)))>>1]);
    }
#pragma unroll
    for (int n=0;n<4;++n){
      const int rb = wn*64+n*16+lr;
      bv[n] = ldsr8(&bb[(rb*64 + ((lg*16) ^ (((rb>>1)&3)<<4)))>>1]);
    }
#pragma unroll
    for (int m=0;m<2;++m)
#pragma unroll
      for (int n=0;n<4;++n)
        acc[m][n] = mfma16(af[m], bv[n], acc[m][n]);
    __syncthreads();
  }
#pragma unroll
  for (int m=0;m<2;++m)
#pragma unroll
    for (int r=0;r<4;++r){
      float s = 0.f, qq = 0.f;
#pragma unroll
      for (int n=0;n<4;++n){
        const int col = wn*64 + n*16 + lr;
        const int row = m0 + wm*32 + m*16 + lg*4 + r;
        float val = acc[m][n][r] + bf2f(bo[col]) + bf2f(batchc[(size_t)row*256 + col]);
        acc[m][n][r] = val;
        s += val; qq += val*val;
      }
#pragma unroll
      for (int x=1;x<16;x<<=1){ s += __shfl_xor(s, x); qq += __shfl_xor(qq, x); }
      if (lr == 0){
        const int lrow = m*16 + lg*4 + r;
        red[wm][lrow][wn][0] = s;
        red[wm][lrow][wn][1] = qq;
      }
    }
  __syncthreads();
#pragma unroll
  for (int m=0;m<2;++m)
#pragma unroll
    for (int r=0;r<4;++r){
      const int lrow = m*16 + lg*4 + r;
      const float S = red[wm][lrow][0][0]+red[wm][lrow][1][0]+red[wm][lrow][2][0]+red[wm][lrow][3][0];
      const float Q = red[wm][lrow][0][1]+red[wm][lrow][1][1]+red[wm][lrow][2][1]+red[wm][lrow][3][1];
      const float mu = S*(1.f/256.f);
      const float rs = rsqrtf(Q*(1.f/256.f) - mu*mu + 1e-5f);
      const int row = m0 + wm*32 + lrow;
      const int msk = cmask[row];
      const size_t prow = (size_t)row + (row>>11)*8 + 4;
#pragma unroll
      for (int n=0;n<4;++n){
        const int col = wn*64 + n*16 + lr;
        float y = (acc[m][n][r]-mu)*rs*bf2f(g1[col]) + bf2f(be1[col]);
        seq1p[prow*256 + col] = msk ? (u16)0 : f2bf(y);
      }
    }
}

// ------- fused conv2 + residual + LayerNorm2 + mask (f32 out) -------
__global__ __launch_bounds__(512)
void conv2_ln(const u16* __restrict__ Hh, const u16* __restrict__ w2c,
              const u16* __restrict__ b2, const u16* __restrict__ seq1p,
              const u16* __restrict__ g2, const u16* __restrict__ be2,
              const u16* __restrict__ cmask, float* __restrict__ out)
{
  __shared__ __align__(16) u16 aL[2][2048];
  __shared__ __align__(16) u16 bL[2][8192];
  __shared__ float red[2][32][4][2];
  const int tid = threadIdx.x, lane = tid&63, w = tid>>6;
  const int wm = w>>2, wn = w&3, lr = lane&15, lg = lane>>4;
  int mi, ni; xcd_remap_bal(32, mi, ni); (void)ni;
  const int m0 = mi*64;
  if (cmask[m0] != 0) return;

  f32x4 acc[2][4];
#pragma unroll
  for (int i=0;i<2;++i)
#pragma unroll
    for (int j=0;j<4;++j) acc[i][j] = f32x4{0.f,0.f,0.f,0.f};

  auto stage = [&](int buf, int kk){
    if (w < 4){
      const int boff = w*1024 + lane*16;
      const int r = boff>>6;
      const int cb = (boff&63) ^ (((r>>1)&3)<<4);
      gll16(&Hh[(size_t)(m0+r)*1024 + kk*32 + (cb>>1)], &aL[buf][w*512]);
    }
#pragma unroll
    for (int i=0;i<2;++i){
      const int chunk = w*2+i;
      const int boff = chunk*1024 + lane*16;
      const int r = boff>>6;
      const int cb = (boff&63) ^ (((r>>1)&3)<<4);
      gll16(&w2c[(size_t)r*1024 + kk*32 + (cb>>1)], &bL[buf][chunk*512]);
    }
  };

  stage(0,0);
  __syncthreads();
  for (int kk=0; kk<32; ++kk){
    if (kk+1<32) stage((kk+1)&1, kk+1);
    const u16* ab = aL[kk&1];
    const u16* bb = bL[kk&1];
    bf16x8 af[2], bv[4];
#pragma unroll
    for (int m=0;m<2;++m){
      const int ra = wm*32+m*16+lr;
      af[m] = ldsr8(&ab[(ra*64 + ((lg*16) ^ (((ra>>1)&3)<<4)))>>1]);
    }
#pragma unroll
    for (int n=0;n<4;++n){
      const int rb = wn*64+n*16+lr;
      bv[n] = ldsr8(&bb[(rb*64 + ((lg*16) ^ (((rb>>1)&3)<<4)))>>1]);
    }
#pragma unroll
    for (int m=0;m<2;++m)
#pragma unroll
      for (int n=0;n<4;++n)
        acc[m][n] = mfma16(af[m], bv[n], acc[m][n]);
    __syncthreads();
  }
#pragma unroll
  for (int m=0;m<2;++m)
#pragma unroll
    for (int r=0;r<4;++r){
      float s = 0.f, qq = 0.f;
#pragma unroll
      for (int n=0;n<4;++n){
        const int col = wn*64 + n*16 + lr;
        const int row = m0 + wm*32 + m*16 + lg*4 + r;
        const size_t ri = ((size_t)row + (row>>11)*8 + 4)*256 + col;
        float val = acc[m][n][r] + bf2f(b2[col]) + bf2f(seq1p[ri]);
        acc[m][n][r] = val;
        s += val; qq += val*val;
      }
#pragma unroll
      for (int x=1;x<16;x<<=1){ s += __shfl_xor(s, x); qq += __shfl_xor(qq, x); }
      if (lr == 0){
        const int lrow = m*16 + lg*4 + r;
        red[wm][lrow][wn][0] = s;
        red[wm][lrow][wn][1] = qq;
      }
    }
  __syncthreads();
#pragma unroll
  for (int m=0;m<2;++m)
#pragma unroll
    for (int r=0;r<4;++r){
      const int lrow = m*16 + lg*4 + r;
      const float S = red[wm][lrow][0][0]+red[wm][lrow][1][0]+red[wm][lrow][2][0]+red[wm][lrow][3][0];
      const float Q = red[wm][lrow][0][1]+red[wm][lrow][1][1]+red[wm][lrow][2][1]+red[wm][lrow][3][1];
      const float mu = S*(1.f/256.f);
      const float rs = rsqrtf(Q*(1.f/256.f) - mu*mu + 1e-5f);
      const int row = m0 + wm*32 + lrow;
      const int msk = cmask[row];
#pragma unroll
      for (int n=0;n<4;++n){
        const int col = wn*64 + n*16 + lr;
        float y = (acc[m][n][r]-mu)*rs*bf2f(g2[col]) + bf2f(be2[col]);
        out[(size_t)row*256 + col] = msk ? 0.f : y;
      }
    }
}

// ------- V [16384][256] -> VT [b][h][128][2048] -------
__global__ __launch_bounds__(256)
void vtrans(const u16* __restrict__ V, u16* __restrict__ VT)
{
  __shared__ u16 t[64][72];
  const int tid = threadIdx.x;
  const int s0 = blockIdx.x*64;
  const int d0 = blockIdx.y*64;
#pragma unroll
  for (int i=0;i<2;++i){
    const int chunk = tid + i*256;
    const int sr = chunk>>3, c8 = (chunk&7)*8;
    u32x4 raw = *(const u32x4*)&V[(size_t)(s0+sr)*256 + d0 + c8];
#pragma unroll
    for (int j=0;j<4;++j){
      t[sr][c8+2*j]   = (u16)(raw[j]&0xffffu);
      t[sr][c8+2*j+1] = (u16)(raw[j]>>16);
    }
  }
  __syncthreads();
  const int b = s0>>11;
#pragma unroll
  for (int i=0;i<2;++i){
    const int chunk = tid + i*256;
    const int dr = chunk>>3, s8 = (chunk&7)*8;
    const int dg = d0 + dr;
    const int hh = dg>>7, dh = dg&127;
    u32x4 o;
#pragma unroll
    for (int j=0;j<4;++j)
      o[j] = (u32)t[s8+2*j][dr] | ((u32)t[s8+2*j+1][dr]<<16);
    *(u32x4*)&VT[((size_t)((b*2+hh)*128 + dh))*2048 + (s0&2047) + s8] = o;
  }
}

// ------- flash attention: q-tile 128, 8 waves, KVBLK=64, dbuf gll16, 1 barrier/tile -------
__global__ __launch_bounds__(512)
void attn_fwd(const u16* __restrict__ Q, const u16* __restrict__ Kb,
              const u16* __restrict__ VT, const u32* __restrict__ lengths,
              u16* __restrict__ ctx)
{
  __shared__ __align__(16) u16 kls[2][64*128];
  __shared__ __align__(16) u16 vtls[2][128*64];
  __shared__ __align__(16) u16 pls[8][16*64];
  const int tid = threadIdx.x, lane = tid&63, w = tid>>6;
  const int fid = blockIdx.x;
  const int pair = fid & 15;
  const int qt = fid >> 4;
  const int b  = pair >> 1;
  const int hh = pair & 1;
  const int q0 = qt*128;
  const int L  = (int)lengths[b];
  if (q0 >= L) return;
  const int nkt = (L + 63) >> 6;
  const int lr = lane&15, lg = lane>>4;
  u16* pw = pls[w];

  bf16x8 qf[4];
#pragma unroll
  for (int d=0;d<4;++d)
    qf[d] = *(const bf16x8*)&Q[((size_t)(b*2048+q0+w*16+lr))*256 + hh*128 + d*32 + lg*8];

  f32x4 oacc[8];
  float mrun[4], lrun[4];
#pragma unroll
  for (int n=0;n<8;++n) oacc[n] = f32x4{0.f,0.f,0.f,0.f};
#pragma unroll
  for (int r=0;r<4;++r){ mrun[r] = -1e30f; lrun[r] = 0.f; }

  const size_t kbase = (size_t)(b*2048)*256 + hh*128;
  const size_t vbase = (size_t)((b*2+hh)*128)*2048;

  auto stage = [&](int buf, int kt){
    const int kv0 = kt*64;
#pragma unroll
    for (int i=0;i<2;++i){
      const int chunk = w*2+i;
      const int boff = chunk*1024 + lane*16;
      const int r = boff>>8;
      const int cb = (boff&255) ^ ((r&7)<<4);
      gll16(&Kb[kbase + (size_t)(kv0+r)*256 + (cb>>1)], &kls[buf][chunk*512]);
    }
#pragma unroll
    for (int i=0;i<2;++i){
      const int chunk = w*2+i;
      const int boff = chunk*1024 + lane*16;
      const int r = boff>>7;
      const int cb = (boff&127) ^ ((r&7)<<4);
      gll16(&VT[vbase + (size_t)r*2048 + kv0 + (cb>>1)], &vtls[buf][chunk*512]);
    }
  };

  stage(0, 0);
  __syncthreads();

  for (int kt=0; kt<nkt; ++kt){
    const int kv0 = kt*64;
    const int buf = kt&1;
    if (kt+1 < nkt) stage(buf^1, kt+1);
    f32x4 sacc[4];
#pragma unroll
    for (int n=0;n<4;++n) sacc[n] = f32x4{0.f,0.f,0.f,0.f};
    __builtin_amdgcn_s_setprio(1);
#pragma unroll
    for (int dk=0;dk<4;++dk){
      bf16x8 bk[4];
#pragma unroll
      for (int n=0;n<4;++n){
        const int rb = n*16+lr;
        bk[n] = ldsr8(&kls[buf][(rb*256 + ((dk*64+lg*16) ^ ((rb&7)<<4)))>>1]);
      }
#pragma unroll
      for (int n=0;n<4;++n)
        sacc[n] = mfma16(qf[dk], bk[n], sacc[n]);
    }
    __builtin_amdgcn_s_setprio(0);
#pragma unroll
    for (int n=0;n<4;++n){
      const float madd = (kv0 + n*16 + lr < L) ? 0.f : -1e30f;
#pragma unroll
      for (int r=0;r<4;++r)
        sacc[n][r] = sacc[n][r]*0.0625f + madd;
    }
#pragma unroll
    for (int r=0;r<4;++r){
      float rm = sacc[0][r];
#pragma unroll
      for (int n=1;n<4;++n) rm = fmaxf(rm, sacc[n][r]);
#pragma unroll
      for (int x=1;x<16;x<<=1) rm = fmaxf(rm, __shfl_xor(rm, x));
      const float mnew = fmaxf(mrun[r], rm);
      const float alpha = __expf(mrun[r] - mnew);
      float rsum = 0.f;
#pragma unroll
      for (int n=0;n<4;++n){
        float p = __expf(sacc[n][r] - mnew);
        sacc[n][r] = p;
        rsum += p;
      }
#pragma unroll
      for (int x=1;x<16;x<<=1) rsum += __shfl_xor(rsum, x);
      lrun[r] = alpha*lrun[r] + rsum;
      mrun[r] = mnew;
#pragma unroll
      for (int n=0;n<8;++n) oacc[n][r] *= alpha;
    }
#pragma unroll
    for (int n=0;n<4;++n)
#pragma unroll
      for (int r=0;r<4;++r){
        const int row = lg*4 + r;
        pw[(row*128 + (((n*16+lr)*2) ^ ((row&7)<<4)))>>1] = f2bf(sacc[n][r]);
      }
    __builtin_amdgcn_s_setprio(1);
#pragma unroll
    for (int ks=0;ks<2;++ks){
      bf16x8 pa = ldsr8(&pw[(lr*128 + ((ks*64+lg*16) ^ ((lr&7)<<4)))>>1]);
#pragma unroll
      for (int n=0;n<8;++n){
        const int rv = n*16+lr;
        bf16x8 bvv = ldsr8(&vtls[buf][(rv*128 + ((ks*64+lg*16) ^ ((rv&7)<<4)))>>1]);
        oacc[n] = mfma16(pa, bvv, oacc[n]);
      }
    }
    __builtin_amdgcn_s_setprio(0);
    __syncthreads();
  }
#pragma unroll
  for (int r=0;r<4;++r){
    const float inv = lrun[r] > 0.f ? 1.f/lrun[r] : 0.f;
    const int row = q0 + w*16 + lg*4 + r;
#pragma unroll
    for (int n=0;n<8;++n){
      const int col = hh*128 + n*16 + lr;
      ctx[((size_t)(b*2048+row))*256 + col] = f2bf(oacc[n][r]*inv);
    }
  }
}

extern "C" void kernel_launch(void* const* d_in, const int* in_sizes, int n_in,
                              void* d_out, int out_size, void* d_ws, size_t ws_size,
                              hipStream_t stream)
{
  (void)in_sizes; (void)n_in; (void)out_size; (void)ws_size;
  const float* batch=(const float*)d_in[0];  const void* mraw = d_in[1];
  const float* wq=(const float*)d_in[2];  const float* bq=(const float*)d_in[3];
  const float* wk=(const float*)d_in[4];  const float* bk=(const float*)d_in[5];
  const float* wv=(const float*)d_in[6];  const float* bvv=(const float*)d_in[7];
  const float* wo=(const float*)d_in[8];  const float* bo=(const float*)d_in[9];
  const float* g1=(const float*)d_in[10]; const float* be1=(const float*)d_in[11];
  const float* w1=(const float*)d_in[12]; const float* b1=(const float*)d_in[13];
  const float* w2=(const float*)d_in[14]; const float* b2=(const float*)d_in[15];
  const float* g2=(const float*)d_in[16]; const float* be2=(const float*)d_in[17];

  char* ws = (char*)d_ws;
  const size_t M = 1024u*1024u;
  u16*   batchc = (u16*)(ws);          // 0..8M   (live until outproj_ln residual)
  u16*   q      = (u16*)(ws + 8*M);    // 8..16M  (dead after attn)
  u16*   kbuf   = (u16*)(ws + 16*M);   // 16..24M (dead after attn)
  u16*   v      = (u16*)(ws + 24*M);   // 24..32M (dead after vtrans)
  u16*   ctx    = (u16*)(ws + 32*M);   // 32..40M (dead after outproj_ln)
  u16*   VT     = (u16*)(ws + 40*M);   // 40..48M (over seq1p region; dead after attn)
  u16*   seq1p  = (u16*)(ws + 40*M);   // 40..48.1M padded [8][2056][256]
  u16*   h      = (u16*)(ws);          // 0..32M  (over batchc..v; live conv1..conv2)
  u16*   wqc    = (u16*)(ws + 49*M);
  u16*   woc    = wqc + 196608;
  u16*   w2c    = wqc + 262144;
  u16*   w1r    = (u16*)(ws + 50*M);
  u16*   params = w1r + 2359296;
  u16*   cmask  = params + 4096;
  u32*   lengths= (u32*)(cmask + 16384);

  dim3 blk(256,1,1);
  dim3 blk512(512,1,1);

  prep_big<<<dim3(13824,1,1), blk, 0, stream>>>(batch, wq, wk, wv, wo, w2, w1,
                                                batchc, wqc, w1r);
  prep_small<<<dim3(2,1,1), blk, 0, stream>>>(bq,bk,bvv,bo,g1,be1,g2,be2,b1,b2,
                                              params, mraw, cmask, lengths);

  gemm_qkv<<<dim3(128,6,1), blk, 0, stream>>>(batchc, wqc, params, q, cmask);

  vtrans<<<dim3(256,4,1), blk, 0, stream>>>(v, VT);

  attn_fwd<<<dim3(256,1,1), blk512, 0, stream>>>(q, kbuf, VT, lengths, ctx);

  zero_halo<<<dim3(64,1,1), blk, 0, stream>>>(seq1p);

  outproj_ln<<<dim3(256,1,1), blk512, 0, stream>>>(ctx, woc, params+768, batchc,
                                                   params+1024, params+1280, cmask, seq1p);

  conv1_gemm<<<dim3(128,8,1), blk, 0, stream>>>(seq1p, w1r, params+2048, h, cmask);

  conv2_ln<<<dim3(256,1,1), blk512, 0, stream>>>(h, w2c, params+3072, seq1p,
                                                 params+1536, params+1792, cmask,
                                                 (float*)d_out);
}